// Round 8
// baseline (187.481 us; speedup 1.0000x reference)
//
#include <hip/hip_runtime.h>

#define E_EDGES 1000000
#define NNODES  100000
#define HID     128
#define NG      31250     // 32-edge groups (old path)
#define NBLK    768       // old-path grid
#define NT      62500     // 16-edge tiles (new path)
#define EBLK    2048      // new-path blocks: 4/CU resident x 2 passes
#define PBLK    512       // node_precompute blocks (grid-stride over 3125 tiles)

typedef float f32x4 __attribute__((ext_vector_type(4)));
typedef float f32x2 __attribute__((ext_vector_type(2)));
typedef short s16x8 __attribute__((ext_vector_type(8)));

typedef __attribute__((address_space(3))) unsigned int lds_u32;
typedef const __attribute__((address_space(1))) unsigned int glb_u32;

__device__ __forceinline__ void gl_lds16(const void* g, void* l) {
  __builtin_amdgcn_global_load_lds((glb_u32*)g, (lds_u32*)l, 16, 0, 0);
}

// float -> bf16, round-to-nearest-even (inputs are finite)
__device__ __forceinline__ unsigned short f2bf(float f) {
  unsigned int u = __float_as_uint(f);
  u += 0x7FFFu + ((u >> 16) & 1u);
  return (unsigned short)(u >> 16);
}

__device__ __forceinline__ unsigned int cvtpk_bf16(float lo, float hi) {
  unsigned int r;
  asm("v_cvt_pk_bf16_f32 %0, %1, %2" : "=v"(r) : "v"(lo), "v"(hi));
  return r;
}

// packed 2xf32 fma (VOP3P, CDNA2+): d = a*b + c
__device__ __forceinline__ f32x2 pkfma(f32x2 a, f32x2 b, f32x2 c) {
  f32x2 d;
  asm("v_pk_fma_f32 %0, %1, %2, %3" : "=v"(d) : "v"(a), "v"(b), "v"(c));
  return d;
}

__device__ __forceinline__ f32x2 mk2(float v) {
  f32x2 r; r[0] = v; r[1] = v; return r;
}

__device__ __forceinline__ float bflo(unsigned int u) {
  return __uint_as_float(u << 16);
}
__device__ __forceinline__ float bfhi(unsigned int u) {
  return __uint_as_float(u & 0xffff0000u);
}

// byte -> float (1 VALU op each)
__device__ __forceinline__ float cvub0(unsigned int u) {
  float r; asm("v_cvt_f32_ubyte0 %0, %1" : "=v"(r) : "v"(u)); return r;
}
__device__ __forceinline__ float cvub1(unsigned int u) {
  float r; asm("v_cvt_f32_ubyte1 %0, %1" : "=v"(r) : "v"(u)); return r;
}
__device__ __forceinline__ float cvub2(unsigned int u) {
  float r; asm("v_cvt_f32_ubyte2 %0, %1" : "=v"(r) : "v"(u)); return r;
}
__device__ __forceinline__ float cvub3(unsigned int u) {
  float r; asm("v_cvt_f32_ubyte3 %0, %1" : "=v"(r) : "v"(u)); return r;
}

__device__ __forceinline__ int4 pack8(float4 a, float4 b) {
  int4 v;
  v.x = (int)((unsigned)f2bf(a.x) | ((unsigned)f2bf(a.y) << 16));
  v.y = (int)((unsigned)f2bf(a.z) | ((unsigned)f2bf(a.w) << 16));
  v.z = (int)((unsigned)f2bf(b.x) | ((unsigned)f2bf(b.y) << 16));
  v.w = (int)((unsigned)f2bf(b.z) | ((unsigned)f2bf(b.w) << 16));
  return v;
}

__global__ void cast_x_kernel(const float* __restrict__ x,
                              unsigned short* __restrict__ xb) {
  int i = blockIdx.x * blockDim.x + threadIdx.x;
  const float4* p = (const float4*)x;
  float4 a = p[2 * i];
  float4 b = p[2 * i + 1];
  int4 v = pack8(a, b);
  ((int4*)xb)[i] = v;
}

// Correct-but-slow insurance path if workspace is tiny.
__global__ void edge_naive(const float* __restrict__ x, const int* __restrict__ ei,
                           const float* __restrict__ attr, const float* __restrict__ W1,
                           const float* __restrict__ b1, const float* __restrict__ W2,
                           const float* __restrict__ b2, const float* __restrict__ W3,
                           const float* __restrict__ b3, float* __restrict__ out) {
  const int e = blockIdx.x * blockDim.x + threadIdx.x;
  if (e >= E_EDGES) return;
  const float* xs = x + (size_t)ei[e] * HID;
  const float* xd = x + (size_t)ei[E_EDGES + e] * HID;
  const float a = attr[e];
  float h1[HID];
  for (int n = 0; n < HID; ++n) {
    float s = b1[n] + a * W1[256 * HID + n];
    for (int k = 0; k < HID; ++k)
      s += xs[k] * W1[k * HID + n] + xd[k] * W1[(128 + k) * HID + n];
    h1[n] = fmaxf(s, 0.f);
  }
  float o = b3[0];
  for (int n2 = 0; n2 < 32; ++n2) {
    float s = b2[n2];
    for (int n = 0; n < HID; ++n) s += h1[n] * W2[n * 32 + n2];
    o += fmaxf(s, 0.f) * W3[n2];
  }
  out[e] = 1.f / (1.f + __expf(-o));
}

// ---------------------------------------------------------------------------
// OLD verified path -- fallback when ws in [25.6, 26.4) MB (moot).
// ---------------------------------------------------------------------------
__launch_bounds__(256, 3)
__global__ void edge_mlp_kernel(const unsigned short* __restrict__ xb,
                                const int* __restrict__ ei,
                                const float* __restrict__ attr,
                                const float* __restrict__ W1,
                                const float* __restrict__ b1,
                                const float* __restrict__ W2,
                                const float* __restrict__ b2,
                                const float* __restrict__ W3,
                                const float* __restrict__ b3,
                                float* __restrict__ out) {
  __shared__ __align__(16) unsigned char ef[2][16384];
  __shared__ __align__(16) unsigned char h1b[2][8704];
  __shared__ float red[2][4][16];

  const int tid  = threadIdx.x;
  const int w    = tid >> 6;
  const int lane = tid & 63;
  const int q    = lane >> 4;
  const int l15  = lane & 15;

  s16x8 B1[2][8];
  float b1v[2], w1l[2];
#pragma unroll
  for (int th = 0; th < 2; ++th) {
    const int nc = w * 32 + th * 16 + l15;
#pragma unroll
    for (int s = 0; s < 8; ++s)
#pragma unroll
      for (int j = 0; j < 8; ++j)
        B1[th][s][j] = (short)f2bf(W1[(s * 32 + q * 8 + j) * HID + nc]);
    b1v[th] = b1[nc];
    w1l[th] = W1[256 * HID + nc];
  }
  const int n2 = (w & 1) * 16 + l15;
  s16x8 B2[4];
#pragma unroll
  for (int s2 = 0; s2 < 4; ++s2)
#pragma unroll
    for (int j = 0; j < 8; ++j) {
      const int e = s2 * 32 + q * 8 + j;
      const int n = (e >> 5) * 32 + (e & 1) * 16 + ((e >> 1) & 15);
      B2[s2][j] = (short)f2bf(W2[n * 32 + n2]);
    }
  const float b2v = b2[n2];
  const float w3v = W3[n2];
  const float b3v = b3[0];

  const int bx = blockIdx.x;
  int nidA[4] = {0, 0, 0, 0}, nidB[4] = {0, 0, 0, 0};
  const int itmax = (NG - 1 - bx) / NBLK + 2;

  {
#pragma unroll
    for (int i = 0; i < 4; ++i) {
      const int f = w * 4 + i;
      nidA[i] = ei[(f >> 3) * E_EDGES + bx * 32 + (f & 7) * 4 + q];
    }
#pragma unroll
    for (int i = 0; i < 4; ++i) {
      const int f = w * 4 + i, m = (f & 7) * 4 + q;
      gl_lds16(xb + (size_t)nidA[i] * HID + ((l15 ^ (m & 7)) << 3),
               &ef[0][f * 1024]);
    }
    const int g1 = bx + NBLK;
    if (g1 < NG) {
#pragma unroll
      for (int i = 0; i < 4; ++i) {
        const int f = w * 4 + i;
        nidB[i] = ei[(f >> 3) * E_EDGES + g1 * 32 + (f & 7) * 4 + q];
      }
    }
  }
  __syncthreads();

#define ITER(IT, P, NIDU, NIDL)                                               \
  {                                                                           \
    const int g   = bx + (IT) * NBLK;                                         \
    const int g1  = g + NBLK;                                                 \
    const int g2  = g + 2 * NBLK;                                             \
    const int gm1 = g - NBLK;                                                 \
    const int gm2 = g - 2 * NBLK;                                             \
    if (g1 < NG) {                                                            \
      _Pragma("unroll") for (int i = 0; i < 4; ++i) {                         \
        const int f = w * 4 + i, m = (f & 7) * 4 + q;                         \
        gl_lds16(xb + (size_t)NIDU[i] * HID + ((l15 ^ (m & 7)) << 3),         \
                 &ef[(P) ^ 1][f * 1024]);                                     \
      }                                                                       \
    }                                                                         \
    if (g2 < NG) {                                                            \
      _Pragma("unroll") for (int i = 0; i < 4; ++i) {                         \
        const int f = w * 4 + i;                                              \
        NIDL[i] = ei[(f >> 3) * E_EDGES + g2 * 32 + (f & 7) * 4 + q];         \
      }                                                                       \
    }                                                                         \
    if (g < NG) {                                                             \
      const f32x4 at0 = *(const f32x4*)(attr + g * 32 + q * 4);               \
      const f32x4 at1 = *(const f32x4*)(attr + g * 32 + 16 + q * 4);          \
      _Pragma("unroll") for (int t = 0; t < 2; ++t) {                         \
        f32x4 a0 = {0.f, 0.f, 0.f, 0.f}, a1 = {0.f, 0.f, 0.f, 0.f};          \
        _Pragma("unroll") for (int s = 0; s < 8; ++s) {                       \
          const int ch = s * 4 + q;                                           \
          const s16x8 A = *(const s16x8*)&ef[P][(ch >> 4) * 8192 + t * 4096   \
              + l15 * 256 + (((ch & 15) ^ (l15 & 7)) << 4)];                  \
          a0 = __builtin_amdgcn_mfma_f32_16x16x32_bf16(A, B1[0][s], a0, 0, 0, 0); \
          a1 = __builtin_amdgcn_mfma_f32_16x16x32_bf16(A, B1[1][s], a1, 0, 0, 0); \
        }                                                                     \
        const f32x4 at = t ? at1 : at0;                                       \
        _Pragma("unroll") for (int r = 0; r < 4; ++r) {                       \
          const float v0 = fmaxf(a0[r] + b1v[0] + at[r] * w1l[0], 0.f);       \
          const float v1 = fmaxf(a1[r] + b1v[1] + at[r] * w1l[1], 0.f);       \
          const unsigned int pk =                                             \
              (unsigned)f2bf(v0) | ((unsigned)f2bf(v1) << 16);                \
          *(unsigned int*)&h1b[P][t * 4352 + (q * 4 + r) * 272                \
                                  + (w * 16 + l15) * 4] = pk;                 \
        }                                                                     \
      }                                                                       \
    }                                                                         \
    if (gm1 >= 0 && gm1 < NG) {                                               \
      const int t = w >> 1;                                                   \
      f32x4 c0 = {0.f, 0.f, 0.f, 0.f};                                        \
      _Pragma("unroll") for (int s2 = 0; s2 < 4; ++s2) {                      \
        const s16x8 A2 = *(const s16x8*)&h1b[(P) ^ 1][t * 4352 + l15 * 272    \
                                                      + s2 * 64 + q * 16];    \
        c0 = __builtin_amdgcn_mfma_f32_16x16x32_bf16(A2, B2[s2], c0, 0, 0, 0); \
      }                                                                       \
      float p0 = fmaxf(c0[0] + b2v, 0.f) * w3v;                               \
      float p1 = fmaxf(c0[1] + b2v, 0.f) * w3v;                               \
      float p2 = fmaxf(c0[2] + b2v, 0.f) * w3v;                               \
      float p3 = fmaxf(c0[3] + b2v, 0.f) * w3v;                               \
      _Pragma("unroll") for (int off = 8; off >= 1; off >>= 1) {              \
        p0 += __shfl_xor(p0, off, 16);                                        \
        p1 += __shfl_xor(p1, off, 16);                                        \
        p2 += __shfl_xor(p2, off, 16);                                        \
        p3 += __shfl_xor(p3, off, 16);                                        \
      }                                                                       \
      if (l15 == 0) {                                                         \
        red[P][w][q * 4 + 0] = p0;                                            \
        red[P][w][q * 4 + 1] = p1;                                            \
        red[P][w][q * 4 + 2] = p2;                                            \
        red[P][w][q * 4 + 3] = p3;                                            \
      }                                                                       \
    }                                                                         \
    if (gm2 >= 0 && tid < 32) {                                               \
      const int tt = tid >> 4, mm = tid & 15;                                 \
      const float sv = red[(P) ^ 1][tt * 2][mm]                               \
                     + red[(P) ^ 1][tt * 2 + 1][mm] + b3v;                    \
      out[gm2 * 32 + tid] = 1.f / (1.f + __expf(-sv));                        \
    }                                                                         \
    __syncthreads();                                                          \
  }

  for (int itb = 0;; itb += 2) {
    ITER(itb, 0, nidB, nidA)
    if (itb >= itmax) break;
    ITER(itb + 1, 1, nidA, nidB)
    if (itb + 1 >= itmax) break;
  }
#undef ITER
}

// ---------------------------------------------------------------------------
// INT8 path. P8[side][node] = 128 bytes (biased u8, per-node-row scale in
// Sa/Sb f32). Byte at pos = c*64+q*16+i holds h1-col (2c+(i>=8))*32+q*8+(i&7)
// -> each consumer lane's 16B load IS its MFMA A-fragment half (natural
// k-order). p = (u-128)*scale.
// ---------------------------------------------------------------------------
__launch_bounds__(256, 2)
__global__ void node_precompute8(const float* __restrict__ x,
                                 const float* __restrict__ W1,
                                 const float* __restrict__ b1,
                                 unsigned char* __restrict__ P8a,
                                 unsigned char* __restrict__ P8b,
                                 float* __restrict__ Sa,
                                 float* __restrict__ Sb) {
  __shared__ __align__(16) unsigned char xs[32 * 272];  // 32 rows bf16 + pad
  __shared__ float pvf[2][32][132];                     // f32 staging (+pad)
  __shared__ float sclh[2][2][32];                      // per-half row max
  __shared__ float sinv[2][32];                         // 127/rowmax
  const int tid = threadIdx.x;
  const int w = tid >> 6, lane = tid & 63, q = lane >> 4, l15 = lane & 15;
  const int sd = w >> 1;          // 0 -> Pa, 1 -> Pb
  const int cb = (w & 1) * 64;    // col base within side

  // weights once per block: wave w covers side cols cb .. cb+63 (4 n-tiles)
  s16x8 Bf[4][4];
  float bh[4];
#pragma unroll
  for (int nt = 0; nt < 4; ++nt) {
    const int c = cb + nt * 16 + l15;
    bh[nt] = 0.5f * b1[c];
#pragma unroll
    for (int s = 0; s < 4; ++s)
#pragma unroll
      for (int j = 0; j < 8; ++j)
        Bf[nt][s][j] = (short)f2bf(W1[(sd * 128 + s * 32 + q * 8 + j) * HID + c]);
  }

  for (int tile = blockIdx.x; tile < NNODES / 32; tile += gridDim.x) {
    const int n0 = tile * 32;
    // stage 32 node rows f32 -> bf16 into LDS
    {
      const int r = tid >> 3, cc = tid & 7;
      const float* src = x + (size_t)(n0 + r) * HID + cc * 16;
      float4 f0 = ((const float4*)src)[0];
      float4 f1 = ((const float4*)src)[1];
      float4 f2 = ((const float4*)src)[2];
      float4 f3 = ((const float4*)src)[3];
      *(int4*)&xs[r * 272 + cc * 32]      = pack8(f0, f1);
      *(int4*)&xs[r * 272 + cc * 32 + 16] = pack8(f2, f3);
    }
    __syncthreads();

#pragma unroll
    for (int mt = 0; mt < 2; ++mt) {
      s16x8 A[4];
#pragma unroll
      for (int s = 0; s < 4; ++s)
        A[s] = *(const s16x8*)&xs[(mt * 16 + l15) * 272 + (s * 4 + q) * 16];
      float pv[4][4];
#pragma unroll
      for (int nt = 0; nt < 4; ++nt) {
        f32x4 acc = {0.f, 0.f, 0.f, 0.f};
#pragma unroll
        for (int s = 0; s < 4; ++s)
          acc = __builtin_amdgcn_mfma_f32_16x16x32_bf16(A[s], Bf[nt][s], acc, 0, 0, 0);
#pragma unroll
        for (int r = 0; r < 4; ++r) pv[nt][r] = acc[r] + bh[nt];
      }
      // stage to LDS f32
#pragma unroll
      for (int nt = 0; nt < 4; ++nt)
#pragma unroll
        for (int r = 0; r < 4; ++r)
          pvf[sd][mt * 16 + q * 4 + r][cb + nt * 16 + l15] = pv[nt][r];
      // per-row max over this wave's 64 cols
      float m4[4];
#pragma unroll
      for (int r = 0; r < 4; ++r)
        m4[r] = fmaxf(fmaxf(fabsf(pv[0][r]), fabsf(pv[1][r])),
                      fmaxf(fabsf(pv[2][r]), fabsf(pv[3][r])));
#pragma unroll
      for (int off = 8; off >= 1; off >>= 1)
#pragma unroll
        for (int r = 0; r < 4; ++r)
          m4[r] = fmaxf(m4[r], __shfl_xor(m4[r], off, 16));
      if (l15 == 0) {
#pragma unroll
        for (int r = 0; r < 4; ++r)
          sclh[sd][w & 1][mt * 16 + q * 4 + r] = m4[r];
      }
    }
    __syncthreads();

    if (tid < 64) {
      const int sdd = tid >> 5, row = tid & 31;
      const float m = fmaxf(sclh[sdd][0][row], sclh[sdd][1][row]);
      (sdd ? Sb : Sa)[n0 + row] = m * (1.f / 127.f);
      sinv[sdd][row] = m > 0.f ? 127.f / m : 0.f;
    }
    __syncthreads();

    // quantize + store: thread -> (side,row,32B-part); coalesced 128B rows
    {
      const int rg = tid >> 2, part = tid & 3;
      const int sdd = rg >> 5, row = rg & 31;
      const float inv = sinv[sdd][row];
      unsigned int dw[8];
#pragma unroll
      for (int bi = 0; bi < 8; ++bi) {
        unsigned int u32v = 0;
#pragma unroll
        for (int bb = 0; bb < 4; ++bb) {
          const int p = part * 32 + bi * 4 + bb;
          const int col = ((p >> 6) * 2 + ((p >> 3) & 1)) * 32
                          + ((p >> 4) & 3) * 8 + (p & 7);
          const int u = (int)rintf(pvf[sdd][row][col] * inv) + 128;
          u32v |= ((unsigned)u & 0xffu) << (8 * bb);
        }
        dw[bi] = u32v;
      }
      unsigned char* dst = (sdd ? P8b : P8a) + (size_t)(n0 + row) * 128 + part * 32;
      *(int4*)dst        = make_int4((int)dw[0], (int)dw[1], (int)dw[2], (int)dw[3]);
      *(int4*)(dst + 16) = make_int4((int)dw[4], (int)dw[5], (int)dw[6], (int)dw[7]);
    }
    __syncthreads();
  }
}

// Independent-wave edge kernel, int8 gather. Depth-2 register pipeline.
// Dequant via v_cvt_f32_ubyte + PACKED v_pk_fma_f32 (2 cols/op), W1-attr
// column kept as f32 pairs (no bf16 unpack). 4 blocks/CU (R7: VALU 63% at
// 3/CU -> add a wave; VGPR ~100 < 128 budget, no spill).
__launch_bounds__(256, 4)
__global__ void edge_mlp3(const unsigned char* __restrict__ P8a,
                          const unsigned char* __restrict__ P8b,
                          const float* __restrict__ Sa,
                          const float* __restrict__ Sb,
                          const int* __restrict__ ei,
                          const float* __restrict__ attr,
                          const float* __restrict__ W1,
                          const float* __restrict__ W2,
                          const float* __restrict__ b2,
                          const float* __restrict__ W3,
                          const float* __restrict__ b3,
                          float* __restrict__ out) {
  const int tid = threadIdx.x;
  const int w = tid >> 6, lane = tid & 63, q = lane >> 4, l15 = lane & 15;
  const int wid = blockIdx.x * 4 + w;
  const int nw  = EBLK * 4;

  // L2 weight fragments, natural k-order: element (s,j) -> k = s*32+q*8+j
  s16x8 B2a[4], B2b[4];
#pragma unroll
  for (int s = 0; s < 4; ++s)
#pragma unroll
    for (int j = 0; j < 8; ++j) {
      const int k = s * 32 + q * 8 + j;
      B2a[s][j] = (short)f2bf(W2[k * 32 + l15]);
      B2b[s][j] = (short)f2bf(W2[k * 32 + 16 + l15]);
    }
  // attr column of W1 (k=256) as f32 PAIRS: w1f2[s][p] = {w(k0), w(k0+1)},
  // k0 = s*32 + q*8 + 2p  (feeds pk_fma directly, no unpack)
  f32x2 w1f2[4][4];
#pragma unroll
  for (int s = 0; s < 4; ++s)
#pragma unroll
    for (int p = 0; p < 4; ++p) {
      const int k = s * 32 + q * 8 + 2 * p;
      w1f2[s][p][0] = W1[256 * HID + k];
      w1f2[s][p][1] = W1[256 * HID + k + 1];
    }
  const float b2a = b2[l15], b2b = b2[16 + l15];
  const float w3a = W3[l15], w3b = W3[16 + l15];
  const float b3v = b3[0];

  int t = wid;
  if (t >= NT) return;

#define IDS(T, SID, DID, AT)                                                  \
  {                                                                           \
    const int tt_ = (T) < NT ? (T) : NT - 1;                                  \
    SID = ei[tt_ * 16 + l15];                                                 \
    DID = ei[E_EDGES + tt_ * 16 + l15];                                       \
    AT  = attr[tt_ * 16 + l15];                                               \
  }

#define GATH(LA, LB, SAv, SBv, SID, DID)                                      \
  {                                                                           \
    const unsigned char* pa_ = P8a + (size_t)(SID) * 128 + q * 16;            \
    const unsigned char* pb_ = P8b + (size_t)(DID) * 128 + q * 16;            \
    LA[0] = *(const int4*)pa_;                                                \
    LA[1] = *(const int4*)(pa_ + 64);                                         \
    LB[0] = *(const int4*)pb_;                                                \
    LB[1] = *(const int4*)(pb_ + 64);                                         \
    SAv = Sa[SID];                                                            \
    SBv = Sb[DID];                                                            \
  }

#define COMP(T, LA, LB, SAv, SBv, ATV)                                        \
  {                                                                           \
    const f32x2 sa2 = mk2(SAv), sb2 = mk2(SBv), at2 = mk2(ATV);               \
    const f32x2 kq2 = mk2(-128.f * ((SAv) + (SBv)));                          \
    f32x4 c0 = {0.f, 0.f, 0.f, 0.f}, c1 = {0.f, 0.f, 0.f, 0.f};              \
    _Pragma("unroll") for (int s = 0; s < 4; ++s) {                           \
      const int* la_ = (const int*)&LA[s >> 1];                               \
      const int* lb_ = (const int*)&LB[s >> 1];                               \
      int4 afi;                                                               \
      unsigned int* af = (unsigned int*)&afi;                                 \
      _Pragma("unroll") for (int dd = 0; dd < 2; ++dd) {                      \
        const unsigned int ua = (unsigned int)la_[(s & 1) * 2 + dd];          \
        const unsigned int ub = (unsigned int)lb_[(s & 1) * 2 + dd];          \
        f32x2 fa01, fa23, fb01, fb23;                                         \
        fa01[0] = cvub0(ua); fa01[1] = cvub1(ua);                             \
        fa23[0] = cvub2(ua); fa23[1] = cvub3(ua);                             \
        fb01[0] = cvub0(ub); fb01[1] = cvub1(ub);                             \
        fb23[0] = cvub2(ub); fb23[1] = cvub3(ub);                             \
        f32x2 t01 = pkfma(at2, w1f2[s][2 * dd], kq2);                         \
        f32x2 t23 = pkfma(at2, w1f2[s][2 * dd + 1], kq2);                     \
        t01 = pkfma(sb2, fb01, t01);                                          \
        t23 = pkfma(sb2, fb23, t23);                                          \
        t01 = pkfma(sa2, fa01, t01);                                          \
        t23 = pkfma(sa2, fa23, t23);                                          \
        const float v0 = fmaxf(t01[0], 0.f);                                  \
        const float v1 = fmaxf(t01[1], 0.f);                                  \
        const float v2 = fmaxf(t23[0], 0.f);                                  \
        const float v3 = fmaxf(t23[1], 0.f);                                  \
        af[2 * dd]     = cvtpk_bf16(v0, v1);                                  \
        af[2 * dd + 1] = cvtpk_bf16(v2, v3);                                  \
      }                                                                       \
      const s16x8 A_ = *(const s16x8*)&afi;                                   \
      c0 = __builtin_amdgcn_mfma_f32_16x16x32_bf16(A_, B2a[s], c0, 0, 0, 0);  \
      c1 = __builtin_amdgcn_mfma_f32_16x16x32_bf16(A_, B2b[s], c1, 0, 0, 0);  \
    }                                                                         \
    float p0 = fmaxf(c0[0] + b2a, 0.f) * w3a + fmaxf(c1[0] + b2b, 0.f) * w3b; \
    float p1 = fmaxf(c0[1] + b2a, 0.f) * w3a + fmaxf(c1[1] + b2b, 0.f) * w3b; \
    float p2 = fmaxf(c0[2] + b2a, 0.f) * w3a + fmaxf(c1[2] + b2b, 0.f) * w3b; \
    float p3 = fmaxf(c0[3] + b2a, 0.f) * w3a + fmaxf(c1[3] + b2b, 0.f) * w3b; \
    _Pragma("unroll") for (int off = 8; off >= 1; off >>= 1) {                \
      p0 += __shfl_xor(p0, off, 16);                                          \
      p1 += __shfl_xor(p1, off, 16);                                          \
      p2 += __shfl_xor(p2, off, 16);                                          \
      p3 += __shfl_xor(p3, off, 16);                                          \
    }                                                                         \
    if (l15 == 0) {                                                           \
      float4 o4;                                                              \
      o4.x = 1.f / (1.f + __expf(-(p0 + b3v)));                               \
      o4.y = 1.f / (1.f + __expf(-(p1 + b3v)));                               \
      o4.z = 1.f / (1.f + __expf(-(p2 + b3v)));                               \
      o4.w = 1.f / (1.f + __expf(-(p3 + b3v)));                               \
      *(float4*)&out[(T) * 16 + q * 4] = o4;                                  \
    }                                                                         \
  }

  int4 La0[2], Lb0[2], La1[2], Lb1[2];
  int sid, did;
  float sa0, sb0, sa1, sb1, at0v, at1v, atN;

  IDS(t, sid, did, at0v);
  GATH(La0, Lb0, sa0, sb0, sid, did);
  IDS(t + nw, sid, did, atN);

  while (true) {
    const int t1 = t + nw;
    GATH(La1, Lb1, sa1, sb1, sid, did);
    at1v = atN;
    IDS(t1 + nw, sid, did, atN);
    COMP(t, La0, Lb0, sa0, sb0, at0v);
    if (t1 >= NT) break;

    const int t2 = t1 + nw;
    GATH(La0, Lb0, sa0, sb0, sid, did);
    at0v = atN;
    IDS(t2 + nw, sid, did, atN);
    COMP(t1, La1, Lb1, sa1, sb1, at1v);
    if (t2 >= NT) break;

    t = t2;
  }
#undef IDS
#undef GATH
#undef COMP
}

extern "C" void kernel_launch(void* const* d_in, const int* in_sizes, int n_in,
                              void* d_out, int out_size, void* d_ws, size_t ws_size,
                              hipStream_t stream) {
  const float* x    = (const float*)d_in[0];
  const int*   ei   = (const int*)d_in[1];
  const float* attr = (const float*)d_in[2];
  const float* W1   = (const float*)d_in[3];
  const float* b1   = (const float*)d_in[4];
  const float* W2   = (const float*)d_in[5];
  const float* b2   = (const float*)d_in[6];
  const float* W3   = (const float*)d_in[7];
  const float* b3   = (const float*)d_in[8];
  float* out = (float*)d_out;

  const size_t need8 = (size_t)NNODES * 256 + (size_t)NNODES * 8;         // 26.4 MB
  const size_t need1 = (size_t)NNODES * HID * sizeof(unsigned short);     // 25.6 MB
  if (ws_size >= need8) {
    unsigned char* P8a = (unsigned char*)d_ws;
    unsigned char* P8b = P8a + (size_t)NNODES * 128;
    float* Sa = (float*)(P8a + (size_t)NNODES * 256);
    float* Sb = Sa + NNODES;
    node_precompute8<<<PBLK, 256, 0, stream>>>(x, W1, b1, P8a, P8b, Sa, Sb);
    edge_mlp3<<<EBLK, 256, 0, stream>>>(P8a, P8b, Sa, Sb, ei, attr, W1, W2, b2, W3, b3, out);
  } else if (ws_size >= need1) {
    unsigned short* xb = (unsigned short*)d_ws;
    cast_x_kernel<<<6250, 256, 0, stream>>>(x, xb);
    edge_mlp_kernel<<<NBLK, 256, 0, stream>>>(xb, ei, attr, W1, b1, W2, b2, W3, b3, out);
  } else {
    edge_naive<<<(E_EDGES + 255) / 256, 256, 0, stream>>>(x, ei, attr, W1, b1, W2, b2, W3, b3, out);
  }
}

// Round 9
// 170.804 us; speedup vs baseline: 1.0976x; 1.0976x over previous
//
#include <hip/hip_runtime.h>

#define E_EDGES 1000000
#define NNODES  100000
#define HID     128
#define NG      31250     // 32-edge groups (old path)
#define NBLK    768       // old-path grid
#define NT      62500     // 16-edge tiles (new path)
#define EBLK    1536      // new-path blocks: 3/CU resident (proven; >3 spills)
#define PBLK    512       // node_precompute blocks (grid-stride over 3125 tiles)

typedef float f32x4 __attribute__((ext_vector_type(4)));
typedef float f32x2 __attribute__((ext_vector_type(2)));
typedef short s16x8 __attribute__((ext_vector_type(8)));

typedef __attribute__((address_space(3))) unsigned int lds_u32;
typedef const __attribute__((address_space(1))) unsigned int glb_u32;

__device__ __forceinline__ void gl_lds16(const void* g, void* l) {
  __builtin_amdgcn_global_load_lds((glb_u32*)g, (lds_u32*)l, 16, 0, 0);
}

// float -> bf16, round-to-nearest-even (inputs are finite)
__device__ __forceinline__ unsigned short f2bf(float f) {
  unsigned int u = __float_as_uint(f);
  u += 0x7FFFu + ((u >> 16) & 1u);
  return (unsigned short)(u >> 16);
}

__device__ __forceinline__ unsigned int cvtpk_bf16(float lo, float hi) {
  unsigned int r;
  asm("v_cvt_pk_bf16_f32 %0, %1, %2" : "=v"(r) : "v"(lo), "v"(hi));
  return r;
}

// packed 2xf32 fma (VOP3P, CDNA2+): d = a*b + c
__device__ __forceinline__ f32x2 pkfma(f32x2 a, f32x2 b, f32x2 c) {
  f32x2 d;
  asm("v_pk_fma_f32 %0, %1, %2, %3" : "=v"(d) : "v"(a), "v"(b), "v"(c));
  return d;
}

__device__ __forceinline__ f32x2 mk2(float v) {
  f32x2 r; r[0] = v; r[1] = v; return r;
}

__device__ __forceinline__ float bflo(unsigned int u) {
  return __uint_as_float(u << 16);
}
__device__ __forceinline__ float bfhi(unsigned int u) {
  return __uint_as_float(u & 0xffff0000u);
}

// byte -> float (1 VALU op each)
__device__ __forceinline__ float cvub0(unsigned int u) {
  float r; asm("v_cvt_f32_ubyte0 %0, %1" : "=v"(r) : "v"(u)); return r;
}
__device__ __forceinline__ float cvub1(unsigned int u) {
  float r; asm("v_cvt_f32_ubyte1 %0, %1" : "=v"(r) : "v"(u)); return r;
}
__device__ __forceinline__ float cvub2(unsigned int u) {
  float r; asm("v_cvt_f32_ubyte2 %0, %1" : "=v"(r) : "v"(u)); return r;
}
__device__ __forceinline__ float cvub3(unsigned int u) {
  float r; asm("v_cvt_f32_ubyte3 %0, %1" : "=v"(r) : "v"(u)); return r;
}

__device__ __forceinline__ int4 pack8(float4 a, float4 b) {
  int4 v;
  v.x = (int)((unsigned)f2bf(a.x) | ((unsigned)f2bf(a.y) << 16));
  v.y = (int)((unsigned)f2bf(a.z) | ((unsigned)f2bf(a.w) << 16));
  v.z = (int)((unsigned)f2bf(b.x) | ((unsigned)f2bf(b.y) << 16));
  v.w = (int)((unsigned)f2bf(b.z) | ((unsigned)f2bf(b.w) << 16));
  return v;
}

__global__ void cast_x_kernel(const float* __restrict__ x,
                              unsigned short* __restrict__ xb) {
  int i = blockIdx.x * blockDim.x + threadIdx.x;
  const float4* p = (const float4*)x;
  float4 a = p[2 * i];
  float4 b = p[2 * i + 1];
  int4 v = pack8(a, b);
  ((int4*)xb)[i] = v;
}

// Correct-but-slow insurance path if workspace is tiny.
__global__ void edge_naive(const float* __restrict__ x, const int* __restrict__ ei,
                           const float* __restrict__ attr, const float* __restrict__ W1,
                           const float* __restrict__ b1, const float* __restrict__ W2,
                           const float* __restrict__ b2, const float* __restrict__ W3,
                           const float* __restrict__ b3, float* __restrict__ out) {
  const int e = blockIdx.x * blockDim.x + threadIdx.x;
  if (e >= E_EDGES) return;
  const float* xs = x + (size_t)ei[e] * HID;
  const float* xd = x + (size_t)ei[E_EDGES + e] * HID;
  const float a = attr[e];
  float h1[HID];
  for (int n = 0; n < HID; ++n) {
    float s = b1[n] + a * W1[256 * HID + n];
    for (int k = 0; k < HID; ++k)
      s += xs[k] * W1[k * HID + n] + xd[k] * W1[(128 + k) * HID + n];
    h1[n] = fmaxf(s, 0.f);
  }
  float o = b3[0];
  for (int n2 = 0; n2 < 32; ++n2) {
    float s = b2[n2];
    for (int n = 0; n < HID; ++n) s += h1[n] * W2[n * 32 + n2];
    o += fmaxf(s, 0.f) * W3[n2];
  }
  out[e] = 1.f / (1.f + __expf(-o));
}

// ---------------------------------------------------------------------------
// OLD verified path -- fallback when ws in [25.6, 26.4) MB (moot).
// ---------------------------------------------------------------------------
__launch_bounds__(256, 3)
__global__ void edge_mlp_kernel(const unsigned short* __restrict__ xb,
                                const int* __restrict__ ei,
                                const float* __restrict__ attr,
                                const float* __restrict__ W1,
                                const float* __restrict__ b1,
                                const float* __restrict__ W2,
                                const float* __restrict__ b2,
                                const float* __restrict__ W3,
                                const float* __restrict__ b3,
                                float* __restrict__ out) {
  __shared__ __align__(16) unsigned char ef[2][16384];
  __shared__ __align__(16) unsigned char h1b[2][8704];
  __shared__ float red[2][4][16];

  const int tid  = threadIdx.x;
  const int w    = tid >> 6;
  const int lane = tid & 63;
  const int q    = lane >> 4;
  const int l15  = lane & 15;

  s16x8 B1[2][8];
  float b1v[2], w1l[2];
#pragma unroll
  for (int th = 0; th < 2; ++th) {
    const int nc = w * 32 + th * 16 + l15;
#pragma unroll
    for (int s = 0; s < 8; ++s)
#pragma unroll
      for (int j = 0; j < 8; ++j)
        B1[th][s][j] = (short)f2bf(W1[(s * 32 + q * 8 + j) * HID + nc]);
    b1v[th] = b1[nc];
    w1l[th] = W1[256 * HID + nc];
  }
  const int n2 = (w & 1) * 16 + l15;
  s16x8 B2[4];
#pragma unroll
  for (int s2 = 0; s2 < 4; ++s2)
#pragma unroll
    for (int j = 0; j < 8; ++j) {
      const int e = s2 * 32 + q * 8 + j;
      const int n = (e >> 5) * 32 + (e & 1) * 16 + ((e >> 1) & 15);
      B2[s2][j] = (short)f2bf(W2[n * 32 + n2]);
    }
  const float b2v = b2[n2];
  const float w3v = W3[n2];
  const float b3v = b3[0];

  const int bx = blockIdx.x;
  int nidA[4] = {0, 0, 0, 0}, nidB[4] = {0, 0, 0, 0};
  const int itmax = (NG - 1 - bx) / NBLK + 2;

  {
#pragma unroll
    for (int i = 0; i < 4; ++i) {
      const int f = w * 4 + i;
      nidA[i] = ei[(f >> 3) * E_EDGES + bx * 32 + (f & 7) * 4 + q];
    }
#pragma unroll
    for (int i = 0; i < 4; ++i) {
      const int f = w * 4 + i, m = (f & 7) * 4 + q;
      gl_lds16(xb + (size_t)nidA[i] * HID + ((l15 ^ (m & 7)) << 3),
               &ef[0][f * 1024]);
    }
    const int g1 = bx + NBLK;
    if (g1 < NG) {
#pragma unroll
      for (int i = 0; i < 4; ++i) {
        const int f = w * 4 + i;
        nidB[i] = ei[(f >> 3) * E_EDGES + g1 * 32 + (f & 7) * 4 + q];
      }
    }
  }
  __syncthreads();

#define ITER(IT, P, NIDU, NIDL)                                               \
  {                                                                           \
    const int g   = bx + (IT) * NBLK;                                         \
    const int g1  = g + NBLK;                                                 \
    const int g2  = g + 2 * NBLK;                                             \
    const int gm1 = g - NBLK;                                                 \
    const int gm2 = g - 2 * NBLK;                                             \
    if (g1 < NG) {                                                            \
      _Pragma("unroll") for (int i = 0; i < 4; ++i) {                         \
        const int f = w * 4 + i, m = (f & 7) * 4 + q;                         \
        gl_lds16(xb + (size_t)NIDU[i] * HID + ((l15 ^ (m & 7)) << 3),         \
                 &ef[(P) ^ 1][f * 1024]);                                     \
      }                                                                       \
    }                                                                         \
    if (g2 < NG) {                                                            \
      _Pragma("unroll") for (int i = 0; i < 4; ++i) {                         \
        const int f = w * 4 + i;                                              \
        NIDL[i] = ei[(f >> 3) * E_EDGES + g2 * 32 + (f & 7) * 4 + q];         \
      }                                                                       \
    }                                                                         \
    if (g < NG) {                                                             \
      const f32x4 at0 = *(const f32x4*)(attr + g * 32 + q * 4);               \
      const f32x4 at1 = *(const f32x4*)(attr + g * 32 + 16 + q * 4);          \
      _Pragma("unroll") for (int t = 0; t < 2; ++t) {                         \
        f32x4 a0 = {0.f, 0.f, 0.f, 0.f}, a1 = {0.f, 0.f, 0.f, 0.f};          \
        _Pragma("unroll") for (int s = 0; s < 8; ++s) {                       \
          const int ch = s * 4 + q;                                           \
          const s16x8 A = *(const s16x8*)&ef[P][(ch >> 4) * 8192 + t * 4096   \
              + l15 * 256 + (((ch & 15) ^ (l15 & 7)) << 4)];                  \
          a0 = __builtin_amdgcn_mfma_f32_16x16x32_bf16(A, B1[0][s], a0, 0, 0, 0); \
          a1 = __builtin_amdgcn_mfma_f32_16x16x32_bf16(A, B1[1][s], a1, 0, 0, 0); \
        }                                                                     \
        const f32x4 at = t ? at1 : at0;                                       \
        _Pragma("unroll") for (int r = 0; r < 4; ++r) {                       \
          const float v0 = fmaxf(a0[r] + b1v[0] + at[r] * w1l[0], 0.f);       \
          const float v1 = fmaxf(a1[r] + b1v[1] + at[r] * w1l[1], 0.f);       \
          const unsigned int pk =                                             \
              (unsigned)f2bf(v0) | ((unsigned)f2bf(v1) << 16);                \
          *(unsigned int*)&h1b[P][t * 4352 + (q * 4 + r) * 272                \
                                  + (w * 16 + l15) * 4] = pk;                 \
        }                                                                     \
      }                                                                       \
    }                                                                         \
    if (gm1 >= 0 && gm1 < NG) {                                               \
      const int t = w >> 1;                                                   \
      f32x4 c0 = {0.f, 0.f, 0.f, 0.f};                                        \
      _Pragma("unroll") for (int s2 = 0; s2 < 4; ++s2) {                      \
        const s16x8 A2 = *(const s16x8*)&h1b[(P) ^ 1][t * 4352 + l15 * 272    \
                                                      + s2 * 64 + q * 16];    \
        c0 = __builtin_amdgcn_mfma_f32_16x16x32_bf16(A2, B2[s2], c0, 0, 0, 0); \
      }                                                                       \
      float p0 = fmaxf(c0[0] + b2v, 0.f) * w3v;                               \
      float p1 = fmaxf(c0[1] + b2v, 0.f) * w3v;                               \
      float p2 = fmaxf(c0[2] + b2v, 0.f) * w3v;                               \
      float p3 = fmaxf(c0[3] + b2v, 0.f) * w3v;                               \
      _Pragma("unroll") for (int off = 8; off >= 1; off >>= 1) {              \
        p0 += __shfl_xor(p0, off, 16);                                        \
        p1 += __shfl_xor(p1, off, 16);                                        \
        p2 += __shfl_xor(p2, off, 16);                                        \
        p3 += __shfl_xor(p3, off, 16);                                        \
      }                                                                       \
      if (l15 == 0) {                                                         \
        red[P][w][q * 4 + 0] = p0;                                            \
        red[P][w][q * 4 + 1] = p1;                                            \
        red[P][w][q * 4 + 2] = p2;                                            \
        red[P][w][q * 4 + 3] = p3;                                            \
      }                                                                       \
    }                                                                         \
    if (gm2 >= 0 && tid < 32) {                                               \
      const int tt = tid >> 4, mm = tid & 15;                                 \
      const float sv = red[(P) ^ 1][tt * 2][mm]                               \
                     + red[(P) ^ 1][tt * 2 + 1][mm] + b3v;                    \
      out[gm2 * 32 + tid] = 1.f / (1.f + __expf(-sv));                        \
    }                                                                         \
    __syncthreads();                                                          \
  }

  for (int itb = 0;; itb += 2) {
    ITER(itb, 0, nidB, nidA)
    if (itb >= itmax) break;
    ITER(itb + 1, 1, nidA, nidB)
    if (itb + 1 >= itmax) break;
  }
#undef ITER
}

// ---------------------------------------------------------------------------
// INT8 path. P8[side][node] = 128 bytes (biased u8, per-node-row scale in
// Sa/Sb f32). Byte at pos = c*64+q*16+i holds h1-col (2c+(i>=8))*32+q*8+(i&7)
// -> each consumer lane's 16B load IS its MFMA A-fragment half (natural
// k-order). p = (u-128)*scale.
// ---------------------------------------------------------------------------
__launch_bounds__(256, 2)
__global__ void node_precompute8(const float* __restrict__ x,
                                 const float* __restrict__ W1,
                                 const float* __restrict__ b1,
                                 unsigned char* __restrict__ P8a,
                                 unsigned char* __restrict__ P8b,
                                 float* __restrict__ Sa,
                                 float* __restrict__ Sb) {
  __shared__ __align__(16) unsigned char xs[32 * 272];  // 32 rows bf16 + pad
  __shared__ float pvf[2][32][132];                     // f32 staging (+pad)
  __shared__ float sclh[2][2][32];                      // per-half row max
  __shared__ float sinv[2][32];                         // 127/rowmax
  const int tid = threadIdx.x;
  const int w = tid >> 6, lane = tid & 63, q = lane >> 4, l15 = lane & 15;
  const int sd = w >> 1;          // 0 -> Pa, 1 -> Pb
  const int cb = (w & 1) * 64;    // col base within side

  // weights once per block: wave w covers side cols cb .. cb+63 (4 n-tiles)
  s16x8 Bf[4][4];
  float bh[4];
#pragma unroll
  for (int nt = 0; nt < 4; ++nt) {
    const int c = cb + nt * 16 + l15;
    bh[nt] = 0.5f * b1[c];
#pragma unroll
    for (int s = 0; s < 4; ++s)
#pragma unroll
      for (int j = 0; j < 8; ++j)
        Bf[nt][s][j] = (short)f2bf(W1[(sd * 128 + s * 32 + q * 8 + j) * HID + c]);
  }

  for (int tile = blockIdx.x; tile < NNODES / 32; tile += gridDim.x) {
    const int n0 = tile * 32;
    // stage 32 node rows f32 -> bf16 into LDS
    {
      const int r = tid >> 3, cc = tid & 7;
      const float* src = x + (size_t)(n0 + r) * HID + cc * 16;
      float4 f0 = ((const float4*)src)[0];
      float4 f1 = ((const float4*)src)[1];
      float4 f2 = ((const float4*)src)[2];
      float4 f3 = ((const float4*)src)[3];
      *(int4*)&xs[r * 272 + cc * 32]      = pack8(f0, f1);
      *(int4*)&xs[r * 272 + cc * 32 + 16] = pack8(f2, f3);
    }
    __syncthreads();

#pragma unroll
    for (int mt = 0; mt < 2; ++mt) {
      s16x8 A[4];
#pragma unroll
      for (int s = 0; s < 4; ++s)
        A[s] = *(const s16x8*)&xs[(mt * 16 + l15) * 272 + (s * 4 + q) * 16];
      float pv[4][4];
#pragma unroll
      for (int nt = 0; nt < 4; ++nt) {
        f32x4 acc = {0.f, 0.f, 0.f, 0.f};
#pragma unroll
        for (int s = 0; s < 4; ++s)
          acc = __builtin_amdgcn_mfma_f32_16x16x32_bf16(A[s], Bf[nt][s], acc, 0, 0, 0);
#pragma unroll
        for (int r = 0; r < 4; ++r) pv[nt][r] = acc[r] + bh[nt];
      }
      // stage to LDS f32
#pragma unroll
      for (int nt = 0; nt < 4; ++nt)
#pragma unroll
        for (int r = 0; r < 4; ++r)
          pvf[sd][mt * 16 + q * 4 + r][cb + nt * 16 + l15] = pv[nt][r];
      // per-row max over this wave's 64 cols
      float m4[4];
#pragma unroll
      for (int r = 0; r < 4; ++r)
        m4[r] = fmaxf(fmaxf(fabsf(pv[0][r]), fabsf(pv[1][r])),
                      fmaxf(fabsf(pv[2][r]), fabsf(pv[3][r])));
#pragma unroll
      for (int off = 8; off >= 1; off >>= 1)
#pragma unroll
        for (int r = 0; r < 4; ++r)
          m4[r] = fmaxf(m4[r], __shfl_xor(m4[r], off, 16));
      if (l15 == 0) {
#pragma unroll
        for (int r = 0; r < 4; ++r)
          sclh[sd][w & 1][mt * 16 + q * 4 + r] = m4[r];
      }
    }
    __syncthreads();

    if (tid < 64) {
      const int sdd = tid >> 5, row = tid & 31;
      const float m = fmaxf(sclh[sdd][0][row], sclh[sdd][1][row]);
      (sdd ? Sb : Sa)[n0 + row] = m * (1.f / 127.f);
      sinv[sdd][row] = m > 0.f ? 127.f / m : 0.f;
    }
    __syncthreads();

    // quantize + store: thread -> (side,row,32B-part); coalesced 128B rows
    {
      const int rg = tid >> 2, part = tid & 3;
      const int sdd = rg >> 5, row = rg & 31;
      const float inv = sinv[sdd][row];
      unsigned int dw[8];
#pragma unroll
      for (int bi = 0; bi < 8; ++bi) {
        unsigned int u32v = 0;
#pragma unroll
        for (int bb = 0; bb < 4; ++bb) {
          const int p = part * 32 + bi * 4 + bb;
          const int col = ((p >> 6) * 2 + ((p >> 3) & 1)) * 32
                          + ((p >> 4) & 3) * 8 + (p & 7);
          const int u = (int)rintf(pvf[sdd][row][col] * inv) + 128;
          u32v |= ((unsigned)u & 0xffu) << (8 * bb);
        }
        dw[bi] = u32v;
      }
      unsigned char* dst = (sdd ? P8b : P8a) + (size_t)(n0 + row) * 128 + part * 32;
      *(int4*)dst        = make_int4((int)dw[0], (int)dw[1], (int)dw[2], (int)dw[3]);
      *(int4*)(dst + 16) = make_int4((int)dw[4], (int)dw[5], (int)dw[6], (int)dw[7]);
    }
    __syncthreads();
  }
}

// Independent-wave edge kernel, int8 gather. Depth-2 register pipeline.
// Dequant via v_cvt_f32_ubyte + PACKED v_pk_fma_f32 (2 cols/op), W1-attr
// column as f32 pairs (no bf16 unpack). launch_bounds(256,3): R4/R8 both
// proved any higher bound makes the allocator spill (WRITE_SIZE 20-64MB).
__launch_bounds__(256, 3)
__global__ void edge_mlp3(const unsigned char* __restrict__ P8a,
                          const unsigned char* __restrict__ P8b,
                          const float* __restrict__ Sa,
                          const float* __restrict__ Sb,
                          const int* __restrict__ ei,
                          const float* __restrict__ attr,
                          const float* __restrict__ W1,
                          const float* __restrict__ W2,
                          const float* __restrict__ b2,
                          const float* __restrict__ W3,
                          const float* __restrict__ b3,
                          float* __restrict__ out) {
  const int tid = threadIdx.x;
  const int w = tid >> 6, lane = tid & 63, q = lane >> 4, l15 = lane & 15;
  const int wid = blockIdx.x * 4 + w;
  const int nw  = EBLK * 4;

  // L2 weight fragments, natural k-order: element (s,j) -> k = s*32+q*8+j
  s16x8 B2a[4], B2b[4];
#pragma unroll
  for (int s = 0; s < 4; ++s)
#pragma unroll
    for (int j = 0; j < 8; ++j) {
      const int k = s * 32 + q * 8 + j;
      B2a[s][j] = (short)f2bf(W2[k * 32 + l15]);
      B2b[s][j] = (short)f2bf(W2[k * 32 + 16 + l15]);
    }
  // attr column of W1 (k=256) as f32 PAIRS: w1f2[s][p] = {w(k0), w(k0+1)},
  // k0 = s*32 + q*8 + 2p  (feeds pk_fma directly, no unpack)
  f32x2 w1f2[4][4];
#pragma unroll
  for (int s = 0; s < 4; ++s)
#pragma unroll
    for (int p = 0; p < 4; ++p) {
      const int k = s * 32 + q * 8 + 2 * p;
      w1f2[s][p][0] = W1[256 * HID + k];
      w1f2[s][p][1] = W1[256 * HID + k + 1];
    }
  const float b2a = b2[l15], b2b = b2[16 + l15];
  const float w3a = W3[l15], w3b = W3[16 + l15];
  const float b3v = b3[0];

  int t = wid;
  if (t >= NT) return;

#define IDS(T, SID, DID, AT)                                                  \
  {                                                                           \
    const int tt_ = (T) < NT ? (T) : NT - 1;                                  \
    SID = ei[tt_ * 16 + l15];                                                 \
    DID = ei[E_EDGES + tt_ * 16 + l15];                                       \
    AT  = attr[tt_ * 16 + l15];                                               \
  }

#define GATH(LA, LB, SAv, SBv, SID, DID)                                      \
  {                                                                           \
    const unsigned char* pa_ = P8a + (size_t)(SID) * 128 + q * 16;            \
    const unsigned char* pb_ = P8b + (size_t)(DID) * 128 + q * 16;            \
    LA[0] = *(const int4*)pa_;                                                \
    LA[1] = *(const int4*)(pa_ + 64);                                         \
    LB[0] = *(const int4*)pb_;                                                \
    LB[1] = *(const int4*)(pb_ + 64);                                         \
    SAv = Sa[SID];                                                            \
    SBv = Sb[DID];                                                            \
  }

#define COMP(T, LA, LB, SAv, SBv, ATV)                                        \
  {                                                                           \
    const f32x2 sa2 = mk2(SAv), sb2 = mk2(SBv), at2 = mk2(ATV);               \
    const f32x2 kq2 = mk2(-128.f * ((SAv) + (SBv)));                          \
    f32x4 c0 = {0.f, 0.f, 0.f, 0.f}, c1 = {0.f, 0.f, 0.f, 0.f};              \
    _Pragma("unroll") for (int s = 0; s < 4; ++s) {                           \
      const int* la_ = (const int*)&LA[s >> 1];                               \
      const int* lb_ = (const int*)&LB[s >> 1];                               \
      int4 afi;                                                               \
      unsigned int* af = (unsigned int*)&afi;                                 \
      _Pragma("unroll") for (int dd = 0; dd < 2; ++dd) {                      \
        const unsigned int ua = (unsigned int)la_[(s & 1) * 2 + dd];          \
        const unsigned int ub = (unsigned int)lb_[(s & 1) * 2 + dd];          \
        f32x2 fa01, fa23, fb01, fb23;                                         \
        fa01[0] = cvub0(ua); fa01[1] = cvub1(ua);                             \
        fa23[0] = cvub2(ua); fa23[1] = cvub3(ua);                             \
        fb01[0] = cvub0(ub); fb01[1] = cvub1(ub);                             \
        fb23[0] = cvub2(ub); fb23[1] = cvub3(ub);                             \
        f32x2 t01 = pkfma(at2, w1f2[s][2 * dd], kq2);                         \
        f32x2 t23 = pkfma(at2, w1f2[s][2 * dd + 1], kq2);                     \
        t01 = pkfma(sb2, fb01, t01);                                          \
        t23 = pkfma(sb2, fb23, t23);                                          \
        t01 = pkfma(sa2, fa01, t01);                                          \
        t23 = pkfma(sa2, fa23, t23);                                          \
        const float v0 = fmaxf(t01[0], 0.f);                                  \
        const float v1 = fmaxf(t01[1], 0.f);                                  \
        const float v2 = fmaxf(t23[0], 0.f);                                  \
        const float v3 = fmaxf(t23[1], 0.f);                                  \
        af[2 * dd]     = cvtpk_bf16(v0, v1);                                  \
        af[2 * dd + 1] = cvtpk_bf16(v2, v3);                                  \
      }                                                                       \
      const s16x8 A_ = *(const s16x8*)&afi;                                   \
      c0 = __builtin_amdgcn_mfma_f32_16x16x32_bf16(A_, B2a[s], c0, 0, 0, 0);  \
      c1 = __builtin_amdgcn_mfma_f32_16x16x32_bf16(A_, B2b[s], c1, 0, 0, 0);  \
    }                                                                         \
    float p0 = fmaxf(c0[0] + b2a, 0.f) * w3a + fmaxf(c1[0] + b2b, 0.f) * w3b; \
    float p1 = fmaxf(c0[1] + b2a, 0.f) * w3a + fmaxf(c1[1] + b2b, 0.f) * w3b; \
    float p2 = fmaxf(c0[2] + b2a, 0.f) * w3a + fmaxf(c1[2] + b2b, 0.f) * w3b; \
    float p3 = fmaxf(c0[3] + b2a, 0.f) * w3a + fmaxf(c1[3] + b2b, 0.f) * w3b; \
    _Pragma("unroll") for (int off = 8; off >= 1; off >>= 1) {                \
      p0 += __shfl_xor(p0, off, 16);                                          \
      p1 += __shfl_xor(p1, off, 16);                                          \
      p2 += __shfl_xor(p2, off, 16);                                          \
      p3 += __shfl_xor(p3, off, 16);                                          \
    }                                                                         \
    if (l15 == 0) {                                                           \
      float4 o4;                                                              \
      o4.x = 1.f / (1.f + __expf(-(p0 + b3v)));                               \
      o4.y = 1.f / (1.f + __expf(-(p1 + b3v)));                               \
      o4.z = 1.f / (1.f + __expf(-(p2 + b3v)));                               \
      o4.w = 1.f / (1.f + __expf(-(p3 + b3v)));                               \
      *(float4*)&out[(T) * 16 + q * 4] = o4;                                  \
    }                                                                         \
  }

  int4 La0[2], Lb0[2], La1[2], Lb1[2];
  int sid, did;
  float sa0, sb0, sa1, sb1, at0v, at1v, atN;

  IDS(t, sid, did, at0v);
  GATH(La0, Lb0, sa0, sb0, sid, did);
  IDS(t + nw, sid, did, atN);

  while (true) {
    const int t1 = t + nw;
    GATH(La1, Lb1, sa1, sb1, sid, did);
    at1v = atN;
    IDS(t1 + nw, sid, did, atN);
    COMP(t, La0, Lb0, sa0, sb0, at0v);
    if (t1 >= NT) break;

    const int t2 = t1 + nw;
    GATH(La0, Lb0, sa0, sb0, sid, did);
    at0v = atN;
    IDS(t2 + nw, sid, did, atN);
    COMP(t1, La1, Lb1, sa1, sb1, at1v);
    if (t2 >= NT) break;

    t = t2;
  }
#undef IDS
#undef GATH
#undef COMP
}

extern "C" void kernel_launch(void* const* d_in, const int* in_sizes, int n_in,
                              void* d_out, int out_size, void* d_ws, size_t ws_size,
                              hipStream_t stream) {
  const float* x    = (const float*)d_in[0];
  const int*   ei   = (const int*)d_in[1];
  const float* attr = (const float*)d_in[2];
  const float* W1   = (const float*)d_in[3];
  const float* b1   = (const float*)d_in[4];
  const float* W2   = (const float*)d_in[5];
  const float* b2   = (const float*)d_in[6];
  const float* W3   = (const float*)d_in[7];
  const float* b3   = (const float*)d_in[8];
  float* out = (float*)d_out;

  const size_t need8 = (size_t)NNODES * 256 + (size_t)NNODES * 8;         // 26.4 MB
  const size_t need1 = (size_t)NNODES * HID * sizeof(unsigned short);     // 25.6 MB
  if (ws_size >= need8) {
    unsigned char* P8a = (unsigned char*)d_ws;
    unsigned char* P8b = P8a + (size_t)NNODES * 128;
    float* Sa = (float*)(P8a + (size_t)NNODES * 256);
    float* Sb = Sa + NNODES;
    node_precompute8<<<PBLK, 256, 0, stream>>>(x, W1, b1, P8a, P8b, Sa, Sb);
    edge_mlp3<<<EBLK, 256, 0, stream>>>(P8a, P8b, Sa, Sb, ei, attr, W1, W2, b2, W3, b3, out);
  } else if (ws_size >= need1) {
    unsigned short* xb = (unsigned short*)d_ws;
    cast_x_kernel<<<6250, 256, 0, stream>>>(x, xb);
    edge_mlp_kernel<<<NBLK, 256, 0, stream>>>(xb, ei, attr, W1, b1, W2, b2, W3, b3, out);
  } else {
    edge_naive<<<(E_EDGES + 255) / 256, 256, 0, stream>>>(x, ei, attr, W1, b1, W2, b2, W3, b3, out);
  }
}

// Round 10
// 168.229 us; speedup vs baseline: 1.1144x; 1.0153x over previous
//
#include <hip/hip_runtime.h>

#define E_EDGES 1000000
#define NNODES  100000
#define HID     128
#define NG      31250     // 32-edge groups (old path)
#define NBLK    768       // old-path grid
#define NT      62500     // 16-edge tiles (new path)
#define EBLK    1536      // new-path blocks: 3/CU resident (proven; >3 spills)
#define PBLK    768       // node_precompute blocks: 3/CU x 256 CUs

typedef float f32x4 __attribute__((ext_vector_type(4)));
typedef short s16x8 __attribute__((ext_vector_type(8)));

typedef __attribute__((address_space(3))) unsigned int lds_u32;
typedef const __attribute__((address_space(1))) unsigned int glb_u32;

__device__ __forceinline__ void gl_lds16(const void* g, void* l) {
  __builtin_amdgcn_global_load_lds((glb_u32*)g, (lds_u32*)l, 16, 0, 0);
}

// float -> bf16, round-to-nearest-even (inputs are finite)
__device__ __forceinline__ unsigned short f2bf(float f) {
  unsigned int u = __float_as_uint(f);
  u += 0x7FFFu + ((u >> 16) & 1u);
  return (unsigned short)(u >> 16);
}

__device__ __forceinline__ unsigned int cvtpk_bf16(float lo, float hi) {
  unsigned int r;
  asm("v_cvt_pk_bf16_f32 %0, %1, %2" : "=v"(r) : "v"(lo), "v"(hi));
  return r;
}

__device__ __forceinline__ float bflo(unsigned int u) {
  return __uint_as_float(u << 16);
}
__device__ __forceinline__ float bfhi(unsigned int u) {
  return __uint_as_float(u & 0xffff0000u);
}

// byte -> float (1 VALU op each)
__device__ __forceinline__ float cvub0(unsigned int u) {
  float r; asm("v_cvt_f32_ubyte0 %0, %1" : "=v"(r) : "v"(u)); return r;
}
__device__ __forceinline__ float cvub1(unsigned int u) {
  float r; asm("v_cvt_f32_ubyte1 %0, %1" : "=v"(r) : "v"(u)); return r;
}
__device__ __forceinline__ float cvub2(unsigned int u) {
  float r; asm("v_cvt_f32_ubyte2 %0, %1" : "=v"(r) : "v"(u)); return r;
}
__device__ __forceinline__ float cvub3(unsigned int u) {
  float r; asm("v_cvt_f32_ubyte3 %0, %1" : "=v"(r) : "v"(u)); return r;
}

__device__ __forceinline__ int4 pack8(float4 a, float4 b) {
  int4 v;
  v.x = (int)((unsigned)f2bf(a.x) | ((unsigned)f2bf(a.y) << 16));
  v.y = (int)((unsigned)f2bf(a.z) | ((unsigned)f2bf(a.w) << 16));
  v.z = (int)((unsigned)f2bf(b.x) | ((unsigned)f2bf(b.y) << 16));
  v.w = (int)((unsigned)f2bf(b.z) | ((unsigned)f2bf(b.w) << 16));
  return v;
}

__global__ void cast_x_kernel(const float* __restrict__ x,
                              unsigned short* __restrict__ xb) {
  int i = blockIdx.x * blockDim.x + threadIdx.x;
  const float4* p = (const float4*)x;
  float4 a = p[2 * i];
  float4 b = p[2 * i + 1];
  int4 v = pack8(a, b);
  ((int4*)xb)[i] = v;
}

// Correct-but-slow insurance path if workspace is tiny.
__global__ void edge_naive(const float* __restrict__ x, const int* __restrict__ ei,
                           const float* __restrict__ attr, const float* __restrict__ W1,
                           const float* __restrict__ b1, const float* __restrict__ W2,
                           const float* __restrict__ b2, const float* __restrict__ W3,
                           const float* __restrict__ b3, float* __restrict__ out) {
  const int e = blockIdx.x * blockDim.x + threadIdx.x;
  if (e >= E_EDGES) return;
  const float* xs = x + (size_t)ei[e] * HID;
  const float* xd = x + (size_t)ei[E_EDGES + e] * HID;
  const float a = attr[e];
  float h1[HID];
  for (int n = 0; n < HID; ++n) {
    float s = b1[n] + a * W1[256 * HID + n];
    for (int k = 0; k < HID; ++k)
      s += xs[k] * W1[k * HID + n] + xd[k] * W1[(128 + k) * HID + n];
    h1[n] = fmaxf(s, 0.f);
  }
  float o = b3[0];
  for (int n2 = 0; n2 < 32; ++n2) {
    float s = b2[n2];
    for (int n = 0; n < HID; ++n) s += h1[n] * W2[n * 32 + n2];
    o += fmaxf(s, 0.f) * W3[n2];
  }
  out[e] = 1.f / (1.f + __expf(-o));
}

// ---------------------------------------------------------------------------
// OLD verified path -- fallback when ws in [25.6, 26.4) MB (moot).
// ---------------------------------------------------------------------------
__launch_bounds__(256, 3)
__global__ void edge_mlp_kernel(const unsigned short* __restrict__ xb,
                                const int* __restrict__ ei,
                                const float* __restrict__ attr,
                                const float* __restrict__ W1,
                                const float* __restrict__ b1,
                                const float* __restrict__ W2,
                                const float* __restrict__ b2,
                                const float* __restrict__ W3,
                                const float* __restrict__ b3,
                                float* __restrict__ out) {
  __shared__ __align__(16) unsigned char ef[2][16384];
  __shared__ __align__(16) unsigned char h1b[2][8704];
  __shared__ float red[2][4][16];

  const int tid  = threadIdx.x;
  const int w    = tid >> 6;
  const int lane = tid & 63;
  const int q    = lane >> 4;
  const int l15  = lane & 15;

  s16x8 B1[2][8];
  float b1v[2], w1l[2];
#pragma unroll
  for (int th = 0; th < 2; ++th) {
    const int nc = w * 32 + th * 16 + l15;
#pragma unroll
    for (int s = 0; s < 8; ++s)
#pragma unroll
      for (int j = 0; j < 8; ++j)
        B1[th][s][j] = (short)f2bf(W1[(s * 32 + q * 8 + j) * HID + nc]);
    b1v[th] = b1[nc];
    w1l[th] = W1[256 * HID + nc];
  }
  const int n2 = (w & 1) * 16 + l15;
  s16x8 B2[4];
#pragma unroll
  for (int s2 = 0; s2 < 4; ++s2)
#pragma unroll
    for (int j = 0; j < 8; ++j) {
      const int e = s2 * 32 + q * 8 + j;
      const int n = (e >> 5) * 32 + (e & 1) * 16 + ((e >> 1) & 15);
      B2[s2][j] = (short)f2bf(W2[n * 32 + n2]);
    }
  const float b2v = b2[n2];
  const float w3v = W3[n2];
  const float b3v = b3[0];

  const int bx = blockIdx.x;
  int nidA[4] = {0, 0, 0, 0}, nidB[4] = {0, 0, 0, 0};
  const int itmax = (NG - 1 - bx) / NBLK + 2;

  {
#pragma unroll
    for (int i = 0; i < 4; ++i) {
      const int f = w * 4 + i;
      nidA[i] = ei[(f >> 3) * E_EDGES + bx * 32 + (f & 7) * 4 + q];
    }
#pragma unroll
    for (int i = 0; i < 4; ++i) {
      const int f = w * 4 + i, m = (f & 7) * 4 + q;
      gl_lds16(xb + (size_t)nidA[i] * HID + ((l15 ^ (m & 7)) << 3),
               &ef[0][f * 1024]);
    }
    const int g1 = bx + NBLK;
    if (g1 < NG) {
#pragma unroll
      for (int i = 0; i < 4; ++i) {
        const int f = w * 4 + i;
        nidB[i] = ei[(f >> 3) * E_EDGES + g1 * 32 + (f & 7) * 4 + q];
      }
    }
  }
  __syncthreads();

#define ITER(IT, P, NIDU, NIDL)                                               \
  {                                                                           \
    const int g   = bx + (IT) * NBLK;                                         \
    const int g1  = g + NBLK;                                                 \
    const int g2  = g + 2 * NBLK;                                             \
    const int gm1 = g - NBLK;                                                 \
    const int gm2 = g - 2 * NBLK;                                             \
    if (g1 < NG) {                                                            \
      _Pragma("unroll") for (int i = 0; i < 4; ++i) {                         \
        const int f = w * 4 + i, m = (f & 7) * 4 + q;                         \
        gl_lds16(xb + (size_t)NIDU[i] * HID + ((l15 ^ (m & 7)) << 3),         \
                 &ef[(P) ^ 1][f * 1024]);                                     \
      }                                                                       \
    }                                                                         \
    if (g2 < NG) {                                                            \
      _Pragma("unroll") for (int i = 0; i < 4; ++i) {                         \
        const int f = w * 4 + i;                                              \
        NIDL[i] = ei[(f >> 3) * E_EDGES + g2 * 32 + (f & 7) * 4 + q];         \
      }                                                                       \
    }                                                                         \
    if (g < NG) {                                                             \
      const f32x4 at0 = *(const f32x4*)(attr + g * 32 + q * 4);               \
      const f32x4 at1 = *(const f32x4*)(attr + g * 32 + 16 + q * 4);          \
      _Pragma("unroll") for (int t = 0; t < 2; ++t) {                         \
        f32x4 a0 = {0.f, 0.f, 0.f, 0.f}, a1 = {0.f, 0.f, 0.f, 0.f};          \
        _Pragma("unroll") for (int s = 0; s < 8; ++s) {                       \
          const int ch = s * 4 + q;                                           \
          const s16x8 A = *(const s16x8*)&ef[P][(ch >> 4) * 8192 + t * 4096   \
              + l15 * 256 + (((ch & 15) ^ (l15 & 7)) << 4)];                  \
          a0 = __builtin_amdgcn_mfma_f32_16x16x32_bf16(A, B1[0][s], a0, 0, 0, 0); \
          a1 = __builtin_amdgcn_mfma_f32_16x16x32_bf16(A, B1[1][s], a1, 0, 0, 0); \
        }                                                                     \
        const f32x4 at = t ? at1 : at0;                                       \
        _Pragma("unroll") for (int r = 0; r < 4; ++r) {                       \
          const float v0 = fmaxf(a0[r] + b1v[0] + at[r] * w1l[0], 0.f);       \
          const float v1 = fmaxf(a1[r] + b1v[1] + at[r] * w1l[1], 0.f);       \
          const unsigned int pk =                                             \
              (unsigned)f2bf(v0) | ((unsigned)f2bf(v1) << 16);                \
          *(unsigned int*)&h1b[P][t * 4352 + (q * 4 + r) * 272                \
                                  + (w * 16 + l15) * 4] = pk;                 \
        }                                                                     \
      }                                                                       \
    }                                                                         \
    if (gm1 >= 0 && gm1 < NG) {                                               \
      const int t = w >> 1;                                                   \
      f32x4 c0 = {0.f, 0.f, 0.f, 0.f};                                        \
      _Pragma("unroll") for (int s2 = 0; s2 < 4; ++s2) {                      \
        const s16x8 A2 = *(const s16x8*)&h1b[(P) ^ 1][t * 4352 + l15 * 272    \
                                                      + s2 * 64 + q * 16];    \
        c0 = __builtin_amdgcn_mfma_f32_16x16x32_bf16(A2, B2[s2], c0, 0, 0, 0); \
      }                                                                       \
      float p0 = fmaxf(c0[0] + b2v, 0.f) * w3v;                               \
      float p1 = fmaxf(c0[1] + b2v, 0.f) * w3v;                               \
      float p2 = fmaxf(c0[2] + b2v, 0.f) * w3v;                               \
      float p3 = fmaxf(c0[3] + b2v, 0.f) * w3v;                               \
      _Pragma("unroll") for (int off = 8; off >= 1; off >>= 1) {              \
        p0 += __shfl_xor(p0, off, 16);                                        \
        p1 += __shfl_xor(p1, off, 16);                                        \
        p2 += __shfl_xor(p2, off, 16);                                        \
        p3 += __shfl_xor(p3, off, 16);                                        \
      }                                                                       \
      if (l15 == 0) {                                                         \
        red[P][w][q * 4 + 0] = p0;                                            \
        red[P][w][q * 4 + 1] = p1;                                            \
        red[P][w][q * 4 + 2] = p2;                                            \
        red[P][w][q * 4 + 3] = p3;                                            \
      }                                                                       \
    }                                                                         \
    if (gm2 >= 0 && tid < 32) {                                               \
      const int tt = tid >> 4, mm = tid & 15;                                 \
      const float sv = red[(P) ^ 1][tt * 2][mm]                               \
                     + red[(P) ^ 1][tt * 2 + 1][mm] + b3v;                    \
      out[gm2 * 32 + tid] = 1.f / (1.f + __expf(-sv));                        \
    }                                                                         \
    __syncthreads();                                                          \
  }

  for (int itb = 0;; itb += 2) {
    ITER(itb, 0, nidB, nidA)
    if (itb >= itmax) break;
    ITER(itb + 1, 1, nidA, nidB)
    if (itb + 1 >= itmax) break;
  }
#undef ITER
}

// ---------------------------------------------------------------------------
// INT8 path. P8[side][node] = 128 bytes (biased u8, per-node-row scale in
// Sa/Sb f32). Byte at pos = c*64+q*16+i holds h1-col (2c+(i>=8))*32+q*8+(i&7)
// -> each consumer lane's 16B load IS its MFMA A-fragment half (natural
// k-order). p = (u-128)*scale. 3 blocks/CU (LDS 43.3KB x3 = 129.8KB fits;
// fills the 3-barriers-per-tile stalls with a third resident block).
// ---------------------------------------------------------------------------
__launch_bounds__(256, 3)
__global__ void node_precompute8(const float* __restrict__ x,
                                 const float* __restrict__ W1,
                                 const float* __restrict__ b1,
                                 unsigned char* __restrict__ P8a,
                                 unsigned char* __restrict__ P8b,
                                 float* __restrict__ Sa,
                                 float* __restrict__ Sb) {
  __shared__ __align__(16) unsigned char xs[32 * 272];  // 32 rows bf16 + pad
  __shared__ float pvf[2][32][132];                     // f32 staging (+pad)
  __shared__ float sclh[2][2][32];                      // per-half row max
  __shared__ float sinv[2][32];                         // 127/rowmax
  const int tid = threadIdx.x;
  const int w = tid >> 6, lane = tid & 63, q = lane >> 4, l15 = lane & 15;
  const int sd = w >> 1;          // 0 -> Pa, 1 -> Pb
  const int cb = (w & 1) * 64;    // col base within side

  // weights once per block: wave w covers side cols cb .. cb+63 (4 n-tiles)
  s16x8 Bf[4][4];
  float bh[4];
#pragma unroll
  for (int nt = 0; nt < 4; ++nt) {
    const int c = cb + nt * 16 + l15;
    bh[nt] = 0.5f * b1[c];
#pragma unroll
    for (int s = 0; s < 4; ++s)
#pragma unroll
      for (int j = 0; j < 8; ++j)
        Bf[nt][s][j] = (short)f2bf(W1[(sd * 128 + s * 32 + q * 8 + j) * HID + c]);
  }

  for (int tile = blockIdx.x; tile < NNODES / 32; tile += gridDim.x) {
    const int n0 = tile * 32;
    // stage 32 node rows f32 -> bf16 into LDS
    {
      const int r = tid >> 3, cc = tid & 7;
      const float* src = x + (size_t)(n0 + r) * HID + cc * 16;
      float4 f0 = ((const float4*)src)[0];
      float4 f1 = ((const float4*)src)[1];
      float4 f2 = ((const float4*)src)[2];
      float4 f3 = ((const float4*)src)[3];
      *(int4*)&xs[r * 272 + cc * 32]      = pack8(f0, f1);
      *(int4*)&xs[r * 272 + cc * 32 + 16] = pack8(f2, f3);
    }
    __syncthreads();

#pragma unroll
    for (int mt = 0; mt < 2; ++mt) {
      s16x8 A[4];
#pragma unroll
      for (int s = 0; s < 4; ++s)
        A[s] = *(const s16x8*)&xs[(mt * 16 + l15) * 272 + (s * 4 + q) * 16];
      float pv[4][4];
#pragma unroll
      for (int nt = 0; nt < 4; ++nt) {
        f32x4 acc = {0.f, 0.f, 0.f, 0.f};
#pragma unroll
        for (int s = 0; s < 4; ++s)
          acc = __builtin_amdgcn_mfma_f32_16x16x32_bf16(A[s], Bf[nt][s], acc, 0, 0, 0);
#pragma unroll
        for (int r = 0; r < 4; ++r) pv[nt][r] = acc[r] + bh[nt];
      }
      // stage to LDS f32
#pragma unroll
      for (int nt = 0; nt < 4; ++nt)
#pragma unroll
        for (int r = 0; r < 4; ++r)
          pvf[sd][mt * 16 + q * 4 + r][cb + nt * 16 + l15] = pv[nt][r];
      // per-row max over this wave's 64 cols
      float m4[4];
#pragma unroll
      for (int r = 0; r < 4; ++r)
        m4[r] = fmaxf(fmaxf(fabsf(pv[0][r]), fabsf(pv[1][r])),
                      fmaxf(fabsf(pv[2][r]), fabsf(pv[3][r])));
#pragma unroll
      for (int off = 8; off >= 1; off >>= 1)
#pragma unroll
        for (int r = 0; r < 4; ++r)
          m4[r] = fmaxf(m4[r], __shfl_xor(m4[r], off, 16));
      if (l15 == 0) {
#pragma unroll
        for (int r = 0; r < 4; ++r)
          sclh[sd][w & 1][mt * 16 + q * 4 + r] = m4[r];
      }
    }
    __syncthreads();

    if (tid < 64) {
      const int sdd = tid >> 5, row = tid & 31;
      const float m = fmaxf(sclh[sdd][0][row], sclh[sdd][1][row]);
      (sdd ? Sb : Sa)[n0 + row] = m * (1.f / 127.f);
      sinv[sdd][row] = m > 0.f ? 127.f / m : 0.f;
    }
    __syncthreads();

    // quantize + store: thread -> (side,row,32B-part); coalesced 128B rows
    {
      const int rg = tid >> 2, part = tid & 3;
      const int sdd = rg >> 5, row = rg & 31;
      const float inv = sinv[sdd][row];
      unsigned int dw[8];
#pragma unroll
      for (int bi = 0; bi < 8; ++bi) {
        unsigned int u32v = 0;
#pragma unroll
        for (int bb = 0; bb < 4; ++bb) {
          const int p = part * 32 + bi * 4 + bb;
          const int col = ((p >> 6) * 2 + ((p >> 3) & 1)) * 32
                          + ((p >> 4) & 3) * 8 + (p & 7);
          const int u = (int)rintf(pvf[sdd][row][col] * inv) + 128;
          u32v |= ((unsigned)u & 0xffu) << (8 * bb);
        }
        dw[bi] = u32v;
      }
      unsigned char* dst = (sdd ? P8b : P8a) + (size_t)(n0 + row) * 128 + part * 32;
      *(int4*)dst        = make_int4((int)dw[0], (int)dw[1], (int)dw[2], (int)dw[3]);
      *(int4*)(dst + 16) = make_int4((int)dw[4], (int)dw[5], (int)dw[6], (int)dw[7]);
    }
    __syncthreads();
  }
}

// Independent-wave edge kernel, int8 gather. Depth-2 register pipeline.
// R7-EXACT proven-best variant (58.6 us): scalar fmaf dequant, VGPR 68.
// 4-way ablation result: waves(R5)/depth(R6)/VALU-cut(R9) all null; only
// bytes (R7) moved it -> keep this form, launch_bounds(256,3) mandatory
// (R4/R8: any higher bound spills, WRITE_SIZE 20-64MB).
__launch_bounds__(256, 3)
__global__ void edge_mlp3(const unsigned char* __restrict__ P8a,
                          const unsigned char* __restrict__ P8b,
                          const float* __restrict__ Sa,
                          const float* __restrict__ Sb,
                          const int* __restrict__ ei,
                          const float* __restrict__ attr,
                          const float* __restrict__ W1,
                          const float* __restrict__ W2,
                          const float* __restrict__ b2,
                          const float* __restrict__ W3,
                          const float* __restrict__ b3,
                          float* __restrict__ out) {
  const int tid = threadIdx.x;
  const int w = tid >> 6, lane = tid & 63, q = lane >> 4, l15 = lane & 15;
  const int wid = blockIdx.x * 4 + w;
  const int nw  = EBLK * 4;

  // L2 weight fragments, natural k-order: element (s,j) -> k = s*32+q*8+j
  s16x8 B2a[4], B2b[4];
#pragma unroll
  for (int s = 0; s < 4; ++s)
#pragma unroll
    for (int j = 0; j < 8; ++j) {
      const int k = s * 32 + q * 8 + j;
      B2a[s][j] = (short)f2bf(W2[k * 32 + l15]);
      B2b[s][j] = (short)f2bf(W2[k * 32 + 16 + l15]);
    }
  // attr column of W1 (k=256), bf16 pairs in natural order
  int4 w1p[4];
#pragma unroll
  for (int s = 0; s < 4; ++s) {
    unsigned int uu[4];
#pragma unroll
    for (int m = 0; m < 4; ++m) {
      const int k = s * 32 + q * 8 + 2 * m;
      uu[m] = (unsigned)f2bf(W1[256 * HID + k]) |
              ((unsigned)f2bf(W1[256 * HID + k + 1]) << 16);
    }
    w1p[s] = make_int4((int)uu[0], (int)uu[1], (int)uu[2], (int)uu[3]);
  }
  const float b2a = b2[l15], b2b = b2[16 + l15];
  const float w3a = W3[l15], w3b = W3[16 + l15];
  const float b3v = b3[0];

  int t = wid;
  if (t >= NT) return;

#define IDS(T, SID, DID, AT)                                                  \
  {                                                                           \
    const int tt_ = (T) < NT ? (T) : NT - 1;                                  \
    SID = ei[tt_ * 16 + l15];                                                 \
    DID = ei[E_EDGES + tt_ * 16 + l15];                                       \
    AT  = attr[tt_ * 16 + l15];                                               \
  }

#define GATH(LA, LB, SAv, SBv, SID, DID)                                      \
  {                                                                           \
    const unsigned char* pa_ = P8a + (size_t)(SID) * 128 + q * 16;            \
    const unsigned char* pb_ = P8b + (size_t)(DID) * 128 + q * 16;            \
    LA[0] = *(const int4*)pa_;                                                \
    LA[1] = *(const int4*)(pa_ + 64);                                         \
    LB[0] = *(const int4*)pb_;                                                \
    LB[1] = *(const int4*)(pb_ + 64);                                         \
    SAv = Sa[SID];                                                            \
    SBv = Sb[DID];                                                            \
  }

#define COMP(T, LA, LB, SAv, SBv, ATV)                                        \
  {                                                                           \
    const float kq = -128.f * ((SAv) + (SBv));                                \
    f32x4 c0 = {0.f, 0.f, 0.f, 0.f}, c1 = {0.f, 0.f, 0.f, 0.f};              \
    _Pragma("unroll") for (int s = 0; s < 4; ++s) {                           \
      const int* la_ = (const int*)&LA[s >> 1];                               \
      const int* lb_ = (const int*)&LB[s >> 1];                               \
      const unsigned int* uw = (const unsigned int*)&w1p[s];                  \
      int4 afi;                                                               \
      unsigned int* af = (unsigned int*)&afi;                                 \
      _Pragma("unroll") for (int dd = 0; dd < 2; ++dd) {                      \
        const unsigned int ua = (unsigned int)la_[(s & 1) * 2 + dd];          \
        const unsigned int ub = (unsigned int)lb_[(s & 1) * 2 + dd];          \
        const unsigned int w0 = uw[2 * dd], w1_ = uw[2 * dd + 1];             \
        float v0 = fmaf((SAv), cvub0(ua),                                     \
                        fmaf((SBv), cvub0(ub), fmaf((ATV), bflo(w0), kq)));   \
        float v1 = fmaf((SAv), cvub1(ua),                                     \
                        fmaf((SBv), cvub1(ub), fmaf((ATV), bfhi(w0), kq)));   \
        float v2 = fmaf((SAv), cvub2(ua),                                     \
                        fmaf((SBv), cvub2(ub), fmaf((ATV), bflo(w1_), kq)));  \
        float v3 = fmaf((SAv), cvub3(ua),                                     \
                        fmaf((SBv), cvub3(ub), fmaf((ATV), bfhi(w1_), kq)));  \
        v0 = fmaxf(v0, 0.f); v1 = fmaxf(v1, 0.f);                             \
        v2 = fmaxf(v2, 0.f); v3 = fmaxf(v3, 0.f);                             \
        af[2 * dd]     = cvtpk_bf16(v0, v1);                                  \
        af[2 * dd + 1] = cvtpk_bf16(v2, v3);                                  \
      }                                                                       \
      const s16x8 A_ = *(const s16x8*)&afi;                                   \
      c0 = __builtin_amdgcn_mfma_f32_16x16x32_bf16(A_, B2a[s], c0, 0, 0, 0);  \
      c1 = __builtin_amdgcn_mfma_f32_16x16x32_bf16(A_, B2b[s], c1, 0, 0, 0);  \
    }                                                                         \
    float p0 = fmaxf(c0[0] + b2a, 0.f) * w3a + fmaxf(c1[0] + b2b, 0.f) * w3b; \
    float p1 = fmaxf(c0[1] + b2a, 0.f) * w3a + fmaxf(c1[1] + b2b, 0.f) * w3b; \
    float p2 = fmaxf(c0[2] + b2a, 0.f) * w3a + fmaxf(c1[2] + b2b, 0.f) * w3b; \
    float p3 = fmaxf(c0[3] + b2a, 0.f) * w3a + fmaxf(c1[3] + b2b, 0.f) * w3b; \
    _Pragma("unroll") for (int off = 8; off >= 1; off >>= 1) {                \
      p0 += __shfl_xor(p0, off, 16);                                          \
      p1 += __shfl_xor(p1, off, 16);                                          \
      p2 += __shfl_xor(p2, off, 16);                                          \
      p3 += __shfl_xor(p3, off, 16);                                          \
    }                                                                         \
    if (l15 == 0) {                                                           \
      float4 o4;                                                              \
      o4.x = 1.f / (1.f + __expf(-(p0 + b3v)));                               \
      o4.y = 1.f / (1.f + __expf(-(p1 + b3v)));                               \
      o4.z = 1.f / (1.f + __expf(-(p2 + b3v)));                               \
      o4.w = 1.f / (1.f + __expf(-(p3 + b3v)));                               \
      *(float4*)&out[(T) * 16 + q * 4] = o4;                                  \
    }                                                                         \
  }

  int4 La0[2], Lb0[2], La1[2], Lb1[2];
  int sid, did;
  float sa0, sb0, sa1, sb1, at0v, at1v, atN;

  IDS(t, sid, did, at0v);
  GATH(La0, Lb0, sa0, sb0, sid, did);
  IDS(t + nw, sid, did, atN);

  while (true) {
    const int t1 = t + nw;
    GATH(La1, Lb1, sa1, sb1, sid, did);
    at1v = atN;
    IDS(t1 + nw, sid, did, atN);
    COMP(t, La0, Lb0, sa0, sb0, at0v);
    if (t1 >= NT) break;

    const int t2 = t1 + nw;
    GATH(La0, Lb0, sa0, sb0, sid, did);
    at0v = atN;
    IDS(t2 + nw, sid, did, atN);
    COMP(t1, La1, Lb1, sa1, sb1, at1v);
    if (t2 >= NT) break;

    t = t2;
  }
#undef IDS
#undef GATH
#undef COMP
}

extern "C" void kernel_launch(void* const* d_in, const int* in_sizes, int n_in,
                              void* d_out, int out_size, void* d_ws, size_t ws_size,
                              hipStream_t stream) {
  const float* x    = (const float*)d_in[0];
  const int*   ei   = (const int*)d_in[1];
  const float* attr = (const float*)d_in[2];
  const float* W1   = (const float*)d_in[3];
  const float* b1   = (const float*)d_in[4];
  const float* W2   = (const float*)d_in[5];
  const float* b2   = (const float*)d_in[6];
  const float* W3   = (const float*)d_in[7];
  const float* b3   = (const float*)d_in[8];
  float* out = (float*)d_out;

  const size_t need8 = (size_t)NNODES * 256 + (size_t)NNODES * 8;         // 26.4 MB
  const size_t need1 = (size_t)NNODES * HID * sizeof(unsigned short);     // 25.6 MB
  if (ws_size >= need8) {
    unsigned char* P8a = (unsigned char*)d_ws;
    unsigned char* P8b = P8a + (size_t)NNODES * 128;
    float* Sa = (float*)(P8a + (size_t)NNODES * 256);
    float* Sb = Sa + NNODES;
    node_precompute8<<<PBLK, 256, 0, stream>>>(x, W1, b1, P8a, P8b, Sa, Sb);
    edge_mlp3<<<EBLK, 256, 0, stream>>>(P8a, P8b, Sa, Sb, ei, attr, W1, W2, b2, W3, b3, out);
  } else if (ws_size >= need1) {
    unsigned short* xb = (unsigned short*)d_ws;
    cast_x_kernel<<<6250, 256, 0, stream>>>(x, xb);
    edge_mlp_kernel<<<NBLK, 256, 0, stream>>>(xb, ei, attr, W1, b1, W2, b2, W3, b3, out);
  } else {
    edge_naive<<<(E_EDGES + 255) / 256, 256, 0, stream>>>(x, ei, attr, W1, b1, W2, b2, W3, b3, out);
  }
}

// Round 11
// 167.703 us; speedup vs baseline: 1.1179x; 1.0031x over previous
//
#include <hip/hip_runtime.h>

#define E_EDGES 1000000
#define NNODES  100000
#define HID     128
#define NG      31250     // 32-edge groups (old path)
#define NBLK    768       // old-path grid
#define NT      62500     // 16-edge tiles (new path)
#define EBLK    1536      // new-path blocks: 3/CU resident (proven; >3 spills)
#define PBLK    768       // node_precompute blocks: 3/CU x 256 CUs

typedef float f32x4 __attribute__((ext_vector_type(4)));
typedef short s16x8 __attribute__((ext_vector_type(8)));

typedef __attribute__((address_space(3))) unsigned int lds_u32;
typedef const __attribute__((address_space(1))) unsigned int glb_u32;

__device__ __forceinline__ void gl_lds16(const void* g, void* l) {
  __builtin_amdgcn_global_load_lds((glb_u32*)g, (lds_u32*)l, 16, 0, 0);
}

// float -> bf16, round-to-nearest-even (inputs are finite)
__device__ __forceinline__ unsigned short f2bf(float f) {
  unsigned int u = __float_as_uint(f);
  u += 0x7FFFu + ((u >> 16) & 1u);
  return (unsigned short)(u >> 16);
}

__device__ __forceinline__ unsigned int cvtpk_bf16(float lo, float hi) {
  unsigned int r;
  asm("v_cvt_pk_bf16_f32 %0, %1, %2" : "=v"(r) : "v"(lo), "v"(hi));
  return r;
}

__device__ __forceinline__ float bflo(unsigned int u) {
  return __uint_as_float(u << 16);
}
__device__ __forceinline__ float bfhi(unsigned int u) {
  return __uint_as_float(u & 0xffff0000u);
}

// byte -> float (1 VALU op each)
__device__ __forceinline__ float cvub0(unsigned int u) {
  float r; asm("v_cvt_f32_ubyte0 %0, %1" : "=v"(r) : "v"(u)); return r;
}
__device__ __forceinline__ float cvub1(unsigned int u) {
  float r; asm("v_cvt_f32_ubyte1 %0, %1" : "=v"(r) : "v"(u)); return r;
}
__device__ __forceinline__ float cvub2(unsigned int u) {
  float r; asm("v_cvt_f32_ubyte2 %0, %1" : "=v"(r) : "v"(u)); return r;
}
__device__ __forceinline__ float cvub3(unsigned int u) {
  float r; asm("v_cvt_f32_ubyte3 %0, %1" : "=v"(r) : "v"(u)); return r;
}

__device__ __forceinline__ int4 pack8(float4 a, float4 b) {
  int4 v;
  v.x = (int)((unsigned)f2bf(a.x) | ((unsigned)f2bf(a.y) << 16));
  v.y = (int)((unsigned)f2bf(a.z) | ((unsigned)f2bf(a.w) << 16));
  v.z = (int)((unsigned)f2bf(b.x) | ((unsigned)f2bf(b.y) << 16));
  v.w = (int)((unsigned)f2bf(b.z) | ((unsigned)f2bf(b.w) << 16));
  return v;
}

__global__ void cast_x_kernel(const float* __restrict__ x,
                              unsigned short* __restrict__ xb) {
  int i = blockIdx.x * blockDim.x + threadIdx.x;
  const float4* p = (const float4*)x;
  float4 a = p[2 * i];
  float4 b = p[2 * i + 1];
  int4 v = pack8(a, b);
  ((int4*)xb)[i] = v;
}

// Correct-but-slow insurance path if workspace is tiny.
__global__ void edge_naive(const float* __restrict__ x, const int* __restrict__ ei,
                           const float* __restrict__ attr, const float* __restrict__ W1,
                           const float* __restrict__ b1, const float* __restrict__ W2,
                           const float* __restrict__ b2, const float* __restrict__ W3,
                           const float* __restrict__ b3, float* __restrict__ out) {
  const int e = blockIdx.x * blockDim.x + threadIdx.x;
  if (e >= E_EDGES) return;
  const float* xs = x + (size_t)ei[e] * HID;
  const float* xd = x + (size_t)ei[E_EDGES + e] * HID;
  const float a = attr[e];
  float h1[HID];
  for (int n = 0; n < HID; ++n) {
    float s = b1[n] + a * W1[256 * HID + n];
    for (int k = 0; k < HID; ++k)
      s += xs[k] * W1[k * HID + n] + xd[k] * W1[(128 + k) * HID + n];
    h1[n] = fmaxf(s, 0.f);
  }
  float o = b3[0];
  for (int n2 = 0; n2 < 32; ++n2) {
    float s = b2[n2];
    for (int n = 0; n < HID; ++n) s += h1[n] * W2[n * 32 + n2];
    o += fmaxf(s, 0.f) * W3[n2];
  }
  out[e] = 1.f / (1.f + __expf(-o));
}

// ---------------------------------------------------------------------------
// OLD verified path -- fallback when ws in [25.6, 26.4) MB (moot).
// ---------------------------------------------------------------------------
__launch_bounds__(256, 3)
__global__ void edge_mlp_kernel(const unsigned short* __restrict__ xb,
                                const int* __restrict__ ei,
                                const float* __restrict__ attr,
                                const float* __restrict__ W1,
                                const float* __restrict__ b1,
                                const float* __restrict__ W2,
                                const float* __restrict__ b2,
                                const float* __restrict__ W3,
                                const float* __restrict__ b3,
                                float* __restrict__ out) {
  __shared__ __align__(16) unsigned char ef[2][16384];
  __shared__ __align__(16) unsigned char h1b[2][8704];
  __shared__ float red[2][4][16];

  const int tid  = threadIdx.x;
  const int w    = tid >> 6;
  const int lane = tid & 63;
  const int q    = lane >> 4;
  const int l15  = lane & 15;

  s16x8 B1[2][8];
  float b1v[2], w1l[2];
#pragma unroll
  for (int th = 0; th < 2; ++th) {
    const int nc = w * 32 + th * 16 + l15;
#pragma unroll
    for (int s = 0; s < 8; ++s)
#pragma unroll
      for (int j = 0; j < 8; ++j)
        B1[th][s][j] = (short)f2bf(W1[(s * 32 + q * 8 + j) * HID + nc]);
    b1v[th] = b1[nc];
    w1l[th] = W1[256 * HID + nc];
  }
  const int n2 = (w & 1) * 16 + l15;
  s16x8 B2[4];
#pragma unroll
  for (int s2 = 0; s2 < 4; ++s2)
#pragma unroll
    for (int j = 0; j < 8; ++j) {
      const int e = s2 * 32 + q * 8 + j;
      const int n = (e >> 5) * 32 + (e & 1) * 16 + ((e >> 1) & 15);
      B2[s2][j] = (short)f2bf(W2[n * 32 + n2]);
    }
  const float b2v = b2[n2];
  const float w3v = W3[n2];
  const float b3v = b3[0];

  const int bx = blockIdx.x;
  int nidA[4] = {0, 0, 0, 0}, nidB[4] = {0, 0, 0, 0};
  const int itmax = (NG - 1 - bx) / NBLK + 2;

  {
#pragma unroll
    for (int i = 0; i < 4; ++i) {
      const int f = w * 4 + i;
      nidA[i] = ei[(f >> 3) * E_EDGES + bx * 32 + (f & 7) * 4 + q];
    }
#pragma unroll
    for (int i = 0; i < 4; ++i) {
      const int f = w * 4 + i, m = (f & 7) * 4 + q;
      gl_lds16(xb + (size_t)nidA[i] * HID + ((l15 ^ (m & 7)) << 3),
               &ef[0][f * 1024]);
    }
    const int g1 = bx + NBLK;
    if (g1 < NG) {
#pragma unroll
      for (int i = 0; i < 4; ++i) {
        const int f = w * 4 + i;
        nidB[i] = ei[(f >> 3) * E_EDGES + g1 * 32 + (f & 7) * 4 + q];
      }
    }
  }
  __syncthreads();

#define ITER(IT, P, NIDU, NIDL)                                               \
  {                                                                           \
    const int g   = bx + (IT) * NBLK;                                         \
    const int g1  = g + NBLK;                                                 \
    const int g2  = g + 2 * NBLK;                                             \
    const int gm1 = g - NBLK;                                                 \
    const int gm2 = g - 2 * NBLK;                                             \
    if (g1 < NG) {                                                            \
      _Pragma("unroll") for (int i = 0; i < 4; ++i) {                         \
        const int f = w * 4 + i, m = (f & 7) * 4 + q;                         \
        gl_lds16(xb + (size_t)NIDU[i] * HID + ((l15 ^ (m & 7)) << 3),         \
                 &ef[(P) ^ 1][f * 1024]);                                     \
      }                                                                       \
    }                                                                         \
    if (g2 < NG) {                                                            \
      _Pragma("unroll") for (int i = 0; i < 4; ++i) {                         \
        const int f = w * 4 + i;                                              \
        NIDL[i] = ei[(f >> 3) * E_EDGES + g2 * 32 + (f & 7) * 4 + q];         \
      }                                                                       \
    }                                                                         \
    if (g < NG) {                                                             \
      const f32x4 at0 = *(const f32x4*)(attr + g * 32 + q * 4);               \
      const f32x4 at1 = *(const f32x4*)(attr + g * 32 + 16 + q * 4);          \
      _Pragma("unroll") for (int t = 0; t < 2; ++t) {                         \
        f32x4 a0 = {0.f, 0.f, 0.f, 0.f}, a1 = {0.f, 0.f, 0.f, 0.f};          \
        _Pragma("unroll") for (int s = 0; s < 8; ++s) {                       \
          const int ch = s * 4 + q;                                           \
          const s16x8 A = *(const s16x8*)&ef[P][(ch >> 4) * 8192 + t * 4096   \
              + l15 * 256 + (((ch & 15) ^ (l15 & 7)) << 4)];                  \
          a0 = __builtin_amdgcn_mfma_f32_16x16x32_bf16(A, B1[0][s], a0, 0, 0, 0); \
          a1 = __builtin_amdgcn_mfma_f32_16x16x32_bf16(A, B1[1][s], a1, 0, 0, 0); \
        }                                                                     \
        const f32x4 at = t ? at1 : at0;                                       \
        _Pragma("unroll") for (int r = 0; r < 4; ++r) {                       \
          const float v0 = fmaxf(a0[r] + b1v[0] + at[r] * w1l[0], 0.f);       \
          const float v1 = fmaxf(a1[r] + b1v[1] + at[r] * w1l[1], 0.f);       \
          const unsigned int pk =                                             \
              (unsigned)f2bf(v0) | ((unsigned)f2bf(v1) << 16);                \
          *(unsigned int*)&h1b[P][t * 4352 + (q * 4 + r) * 272                \
                                  + (w * 16 + l15) * 4] = pk;                 \
        }                                                                     \
      }                                                                       \
    }                                                                         \
    if (gm1 >= 0 && gm1 < NG) {                                               \
      const int t = w >> 1;                                                   \
      f32x4 c0 = {0.f, 0.f, 0.f, 0.f};                                        \
      _Pragma("unroll") for (int s2 = 0; s2 < 4; ++s2) {                      \
        const s16x8 A2 = *(const s16x8*)&h1b[(P) ^ 1][t * 4352 + l15 * 272    \
                                                      + s2 * 64 + q * 16];    \
        c0 = __builtin_amdgcn_mfma_f32_16x16x32_bf16(A2, B2[s2], c0, 0, 0, 0); \
      }                                                                       \
      float p0 = fmaxf(c0[0] + b2v, 0.f) * w3v;                               \
      float p1 = fmaxf(c0[1] + b2v, 0.f) * w3v;                               \
      float p2 = fmaxf(c0[2] + b2v, 0.f) * w3v;                               \
      float p3 = fmaxf(c0[3] + b2v, 0.f) * w3v;                               \
      _Pragma("unroll") for (int off = 8; off >= 1; off >>= 1) {              \
        p0 += __shfl_xor(p0, off, 16);                                        \
        p1 += __shfl_xor(p1, off, 16);                                        \
        p2 += __shfl_xor(p2, off, 16);                                        \
        p3 += __shfl_xor(p3, off, 16);                                        \
      }                                                                       \
      if (l15 == 0) {                                                         \
        red[P][w][q * 4 + 0] = p0;                                            \
        red[P][w][q * 4 + 1] = p1;                                            \
        red[P][w][q * 4 + 2] = p2;                                            \
        red[P][w][q * 4 + 3] = p3;                                            \
      }                                                                       \
    }                                                                         \
    if (gm2 >= 0 && tid < 32) {                                               \
      const int tt = tid >> 4, mm = tid & 15;                                 \
      const float sv = red[(P) ^ 1][tt * 2][mm]                               \
                     + red[(P) ^ 1][tt * 2 + 1][mm] + b3v;                    \
      out[gm2 * 32 + tid] = 1.f / (1.f + __expf(-sv));                        \
    }                                                                         \
    __syncthreads();                                                          \
  }

  for (int itb = 0;; itb += 2) {
    ITER(itb, 0, nidB, nidA)
    if (itb >= itmax) break;
    ITER(itb + 1, 1, nidA, nidB)
    if (itb + 1 >= itmax) break;
  }
#undef ITER
}

// ---------------------------------------------------------------------------
// INT8 path. P8[side][node] = 128 bytes (biased u8, per-node-row scale in
// Sa/Sb f32). Byte at pos = c*64+q*16+i holds h1-col (2c+(i>=8))*32+q*8+(i&7)
// -> each consumer lane's 16B load IS its MFMA A-fragment half (natural
// k-order). p = (u-128)*scale.
// R11: register-prefetch next tile's x (hides HBM latency under MFMA+quant
// phases) + 3 barriers/tile (sinv phase folded into quantize: each thread
// computes 127/m itself from sclh).
// ---------------------------------------------------------------------------
__launch_bounds__(256, 3)
__global__ void node_precompute8(const float* __restrict__ x,
                                 const float* __restrict__ W1,
                                 const float* __restrict__ b1,
                                 unsigned char* __restrict__ P8a,
                                 unsigned char* __restrict__ P8b,
                                 float* __restrict__ Sa,
                                 float* __restrict__ Sb) {
  __shared__ __align__(16) unsigned char xs[32 * 272];  // 32 rows bf16 + pad
  __shared__ float pvf[2][32][132];                     // f32 staging (+pad)
  __shared__ float sclh[2][2][32];                      // per-half row max
  const int tid = threadIdx.x;
  const int w = tid >> 6, lane = tid & 63, q = lane >> 4, l15 = lane & 15;
  const int sd = w >> 1;          // 0 -> Pa, 1 -> Pb
  const int cb = (w & 1) * 64;    // col base within side
  const int NTL = NNODES / 32;

  // weights once per block: wave w covers side cols cb .. cb+63 (4 n-tiles)
  s16x8 Bf[4][4];
  float bh[4];
#pragma unroll
  for (int nt = 0; nt < 4; ++nt) {
    const int c = cb + nt * 16 + l15;
    bh[nt] = 0.5f * b1[c];
#pragma unroll
    for (int s = 0; s < 4; ++s)
#pragma unroll
      for (int j = 0; j < 8; ++j)
        Bf[nt][s][j] = (short)f2bf(W1[(sd * 128 + s * 32 + q * 8 + j) * HID + c]);
  }

  const int r = tid >> 3, cc = tid & 7;
  float4 f0, f1, f2, f3;
  int tile = blockIdx.x;
  if (tile < NTL) {
    const float* src = x + (size_t)(tile * 32 + r) * HID + cc * 16;
    f0 = ((const float4*)src)[0];
    f1 = ((const float4*)src)[1];
    f2 = ((const float4*)src)[2];
    f3 = ((const float4*)src)[3];
  }

  for (; tile < NTL; tile += gridDim.x) {
    const int n0 = tile * 32;
    // phase 1: prefetched regs -> LDS (bf16)
    *(int4*)&xs[r * 272 + cc * 32]      = pack8(f0, f1);
    *(int4*)&xs[r * 272 + cc * 32 + 16] = pack8(f2, f3);
    __syncthreads();

    // issue next tile's x loads now; they complete under MFMA+quantize
    const int tn = tile + gridDim.x;
    if (tn < NTL) {
      const float* src2 = x + (size_t)(tn * 32 + r) * HID + cc * 16;
      f0 = ((const float4*)src2)[0];
      f1 = ((const float4*)src2)[1];
      f2 = ((const float4*)src2)[2];
      f3 = ((const float4*)src2)[3];
    }

    // phase 2: MFMA + pvf stage + per-row max
#pragma unroll
    for (int mt = 0; mt < 2; ++mt) {
      s16x8 A[4];
#pragma unroll
      for (int s = 0; s < 4; ++s)
        A[s] = *(const s16x8*)&xs[(mt * 16 + l15) * 272 + (s * 4 + q) * 16];
      float pv[4][4];
#pragma unroll
      for (int nt = 0; nt < 4; ++nt) {
        f32x4 acc = {0.f, 0.f, 0.f, 0.f};
#pragma unroll
        for (int s = 0; s < 4; ++s)
          acc = __builtin_amdgcn_mfma_f32_16x16x32_bf16(A[s], Bf[nt][s], acc, 0, 0, 0);
#pragma unroll
        for (int rr = 0; rr < 4; ++rr) pv[nt][rr] = acc[rr] + bh[nt];
      }
#pragma unroll
      for (int nt = 0; nt < 4; ++nt)
#pragma unroll
        for (int rr = 0; rr < 4; ++rr)
          pvf[sd][mt * 16 + q * 4 + rr][cb + nt * 16 + l15] = pv[nt][rr];
      float m4[4];
#pragma unroll
      for (int rr = 0; rr < 4; ++rr)
        m4[rr] = fmaxf(fmaxf(fabsf(pv[0][rr]), fabsf(pv[1][rr])),
                       fmaxf(fabsf(pv[2][rr]), fabsf(pv[3][rr])));
#pragma unroll
      for (int off = 8; off >= 1; off >>= 1)
#pragma unroll
        for (int rr = 0; rr < 4; ++rr)
          m4[rr] = fmaxf(m4[rr], __shfl_xor(m4[rr], off, 16));
      if (l15 == 0) {
#pragma unroll
        for (int rr = 0; rr < 4; ++rr)
          sclh[sd][w & 1][mt * 16 + q * 4 + rr] = m4[rr];
      }
    }
    __syncthreads();

    // phase 3: quantize + store (each thread derives its own 127/m)
    {
      const int rg = tid >> 2, part = tid & 3;
      const int sdd = rg >> 5, row = rg & 31;
      const float m = fmaxf(sclh[sdd][0][row], sclh[sdd][1][row]);
      const float inv = m > 0.f ? 127.f / m : 0.f;
      if (part == 0) (sdd ? Sb : Sa)[n0 + row] = m * (1.f / 127.f);
      unsigned int dw[8];
#pragma unroll
      for (int bi = 0; bi < 8; ++bi) {
        unsigned int u32v = 0;
#pragma unroll
        for (int bb = 0; bb < 4; ++bb) {
          const int p = part * 32 + bi * 4 + bb;
          const int col = ((p >> 6) * 2 + ((p >> 3) & 1)) * 32
                          + ((p >> 4) & 3) * 8 + (p & 7);
          const int u = (int)rintf(pvf[sdd][row][col] * inv) + 128;
          u32v |= ((unsigned)u & 0xffu) << (8 * bb);
        }
        dw[bi] = u32v;
      }
      unsigned char* dst = (sdd ? P8b : P8a) + (size_t)(n0 + row) * 128 + part * 32;
      *(int4*)dst        = make_int4((int)dw[0], (int)dw[1], (int)dw[2], (int)dw[3]);
      *(int4*)(dst + 16) = make_int4((int)dw[4], (int)dw[5], (int)dw[6], (int)dw[7]);
    }
    __syncthreads();
  }
}

// Independent-wave edge kernel, int8 gather. Depth-2 register pipeline.
// R7-EXACT proven-best variant (56.5 us): scalar fmaf dequant, VGPR 68.
// 4-way ablation result: waves(R5)/depth(R6)/VALU-cut(R9) all null; only
// bytes (R7) moved it -> keep this form, launch_bounds(256,3) mandatory
// (R4/R8: any higher bound spills, WRITE_SIZE 20-64MB).
__launch_bounds__(256, 3)
__global__ void edge_mlp3(const unsigned char* __restrict__ P8a,
                          const unsigned char* __restrict__ P8b,
                          const float* __restrict__ Sa,
                          const float* __restrict__ Sb,
                          const int* __restrict__ ei,
                          const float* __restrict__ attr,
                          const float* __restrict__ W1,
                          const float* __restrict__ W2,
                          const float* __restrict__ b2,
                          const float* __restrict__ W3,
                          const float* __restrict__ b3,
                          float* __restrict__ out) {
  const int tid = threadIdx.x;
  const int w = tid >> 6, lane = tid & 63, q = lane >> 4, l15 = lane & 15;
  const int wid = blockIdx.x * 4 + w;
  const int nw  = EBLK * 4;

  // L2 weight fragments, natural k-order: element (s,j) -> k = s*32+q*8+j
  s16x8 B2a[4], B2b[4];
#pragma unroll
  for (int s = 0; s < 4; ++s)
#pragma unroll
    for (int j = 0; j < 8; ++j) {
      const int k = s * 32 + q * 8 + j;
      B2a[s][j] = (short)f2bf(W2[k * 32 + l15]);
      B2b[s][j] = (short)f2bf(W2[k * 32 + 16 + l15]);
    }
  // attr column of W1 (k=256), bf16 pairs in natural order
  int4 w1p[4];
#pragma unroll
  for (int s = 0; s < 4; ++s) {
    unsigned int uu[4];
#pragma unroll
    for (int m = 0; m < 4; ++m) {
      const int k = s * 32 + q * 8 + 2 * m;
      uu[m] = (unsigned)f2bf(W1[256 * HID + k]) |
              ((unsigned)f2bf(W1[256 * HID + k + 1]) << 16);
    }
    w1p[s] = make_int4((int)uu[0], (int)uu[1], (int)uu[2], (int)uu[3]);
  }
  const float b2a = b2[l15], b2b = b2[16 + l15];
  const float w3a = W3[l15], w3b = W3[16 + l15];
  const float b3v = b3[0];

  int t = wid;
  if (t >= NT) return;

#define IDS(T, SID, DID, AT)                                                  \
  {                                                                           \
    const int tt_ = (T) < NT ? (T) : NT - 1;                                  \
    SID = ei[tt_ * 16 + l15];                                                 \
    DID = ei[E_EDGES + tt_ * 16 + l15];                                       \
    AT  = attr[tt_ * 16 + l15];                                               \
  }

#define GATH(LA, LB, SAv, SBv, SID, DID)                                      \
  {                                                                           \
    const unsigned char* pa_ = P8a + (size_t)(SID) * 128 + q * 16;            \
    const unsigned char* pb_ = P8b + (size_t)(DID) * 128 + q * 16;            \
    LA[0] = *(const int4*)pa_;                                                \
    LA[1] = *(const int4*)(pa_ + 64);                                         \
    LB[0] = *(const int4*)pb_;                                                \
    LB[1] = *(const int4*)(pb_ + 64);                                         \
    SAv = Sa[SID];                                                            \
    SBv = Sb[DID];                                                            \
  }

#define COMP(T, LA, LB, SAv, SBv, ATV)                                        \
  {                                                                           \
    const float kq = -128.f * ((SAv) + (SBv));                                \
    f32x4 c0 = {0.f, 0.f, 0.f, 0.f}, c1 = {0.f, 0.f, 0.f, 0.f};              \
    _Pragma("unroll") for (int s = 0; s < 4; ++s) {                           \
      const int* la_ = (const int*)&LA[s >> 1];                               \
      const int* lb_ = (const int*)&LB[s >> 1];                               \
      const unsigned int* uw = (const unsigned int*)&w1p[s];                  \
      int4 afi;                                                               \
      unsigned int* af = (unsigned int*)&afi;                                 \
      _Pragma("unroll") for (int dd = 0; dd < 2; ++dd) {                      \
        const unsigned int ua = (unsigned int)la_[(s & 1) * 2 + dd];          \
        const unsigned int ub = (unsigned int)lb_[(s & 1) * 2 + dd];          \
        const unsigned int w0 = uw[2 * dd], w1_ = uw[2 * dd + 1];             \
        float v0 = fmaf((SAv), cvub0(ua),                                     \
                        fmaf((SBv), cvub0(ub), fmaf((ATV), bflo(w0), kq)));   \
        float v1 = fmaf((SAv), cvub1(ua),                                     \
                        fmaf((SBv), cvub1(ub), fmaf((ATV), bfhi(w0), kq)));   \
        float v2 = fmaf((SAv), cvub2(ua),                                     \
                        fmaf((SBv), cvub2(ub), fmaf((ATV), bflo(w1_), kq)));  \
        float v3 = fmaf((SAv), cvub3(ua),                                     \
                        fmaf((SBv), cvub3(ub), fmaf((ATV), bfhi(w1_), kq)));  \
        v0 = fmaxf(v0, 0.f); v1 = fmaxf(v1, 0.f);                             \
        v2 = fmaxf(v2, 0.f); v3 = fmaxf(v3, 0.f);                             \
        af[2 * dd]     = cvtpk_bf16(v0, v1);                                  \
        af[2 * dd + 1] = cvtpk_bf16(v2, v3);                                  \
      }                                                                       \
      const s16x8 A_ = *(const s16x8*)&afi;                                   \
      c0 = __builtin_amdgcn_mfma_f32_16x16x32_bf16(A_, B2a[s], c0, 0, 0, 0);  \
      c1 = __builtin_amdgcn_mfma_f32_16x16x32_bf16(A_, B2b[s], c1, 0, 0, 0);  \
    }                                                                         \
    float p0 = fmaxf(c0[0] + b2a, 0.f) * w3a + fmaxf(c1[0] + b2b, 0.f) * w3b; \
    float p1 = fmaxf(c0[1] + b2a, 0.f) * w3a + fmaxf(c1[1] + b2b, 0.f) * w3b; \
    float p2 = fmaxf(c0[2] + b2a, 0.f) * w3a + fmaxf(c1[2] + b2b, 0.f) * w3b; \
    float p3 = fmaxf(c0[3] + b2a, 0.f) * w3a + fmaxf(c1[3] + b2b, 0.f) * w3b; \
    _Pragma("unroll") for (int off = 8; off >= 1; off >>= 1) {                \
      p0 += __shfl_xor(p0, off, 16);                                          \
      p1 += __shfl_xor(p1, off, 16);                                          \
      p2 += __shfl_xor(p2, off, 16);                                          \
      p3 += __shfl_xor(p3, off, 16);                                          \
    }                                                                         \
    if (l15 == 0) {                                                           \
      float4 o4;                                                              \
      o4.x = 1.f / (1.f + __expf(-(p0 + b3v)));                               \
      o4.y = 1.f / (1.f + __expf(-(p1 + b3v)));                               \
      o4.z = 1.f / (1.f + __expf(-(p2 + b3v)));                               \
      o4.w = 1.f / (1.f + __expf(-(p3 + b3v)));                               \
      *(float4*)&out[(T) * 16 + q * 4] = o4;                                  \
    }                                                                         \
  }

  int4 La0[2], Lb0[2], La1[2], Lb1[2];
  int sid, did;
  float sa0, sb0, sa1, sb1, at0v, at1v, atN;

  IDS(t, sid, did, at0v);
  GATH(La0, Lb0, sa0, sb0, sid, did);
  IDS(t + nw, sid, did, atN);

  while (true) {
    const int t1 = t + nw;
    GATH(La1, Lb1, sa1, sb1, sid, did);
    at1v = atN;
    IDS(t1 + nw, sid, did, atN);
    COMP(t, La0, Lb0, sa0, sb0, at0v);
    if (t1 >= NT) break;

    const int t2 = t1 + nw;
    GATH(La0, Lb0, sa0, sb0, sid, did);
    at0v = atN;
    IDS(t2 + nw, sid, did, atN);
    COMP(t1, La1, Lb1, sa1, sb1, at1v);
    if (t2 >= NT) break;

    t = t2;
  }
#undef IDS
#undef GATH
#undef COMP
}

extern "C" void kernel_launch(void* const* d_in, const int* in_sizes, int n_in,
                              void* d_out, int out_size, void* d_ws, size_t ws_size,
                              hipStream_t stream) {
  const float* x    = (const float*)d_in[0];
  const int*   ei   = (const int*)d_in[1];
  const float* attr = (const float*)d_in[2];
  const float* W1   = (const float*)d_in[3];
  const float* b1   = (const float*)d_in[4];
  const float* W2   = (const float*)d_in[5];
  const float* b2   = (const float*)d_in[6];
  const float* W3   = (const float*)d_in[7];
  const float* b3   = (const float*)d_in[8];
  float* out = (float*)d_out;

  const size_t need8 = (size_t)NNODES * 256 + (size_t)NNODES * 8;         // 26.4 MB
  const size_t need1 = (size_t)NNODES * HID * sizeof(unsigned short);     // 25.6 MB
  if (ws_size >= need8) {
    unsigned char* P8a = (unsigned char*)d_ws;
    unsigned char* P8b = P8a + (size_t)NNODES * 128;
    float* Sa = (float*)(P8a + (size_t)NNODES * 256);
    float* Sb = Sa + NNODES;
    node_precompute8<<<PBLK, 256, 0, stream>>>(x, W1, b1, P8a, P8b, Sa, Sb);
    edge_mlp3<<<EBLK, 256, 0, stream>>>(P8a, P8b, Sa, Sb, ei, attr, W1, W2, b2, W3, b3, out);
  } else if (ws_size >= need1) {
    unsigned short* xb = (unsigned short*)d_ws;
    cast_x_kernel<<<6250, 256, 0, stream>>>(x, xb);
    edge_mlp_kernel<<<NBLK, 256, 0, stream>>>(xb, ei, attr, W1, b1, W2, b2, W3, b3, out);
  } else {
    edge_naive<<<(E_EDGES + 255) / 256, 256, 0, stream>>>(x, ei, attr, W1, b1, W2, b2, W3, b3, out);
  }
}